// Round 6
// baseline (267.355 us; speedup 1.0000x reference)
//
#include <hip/hip_runtime.h>

#define B_ 4
#define S_ 2048
#define D_ 1024
#define H_ 16
#define HS_ 64

typedef float f32x4 __attribute__((ext_vector_type(4)));
typedef short bf16x8 __attribute__((ext_vector_type(8)));

__device__ inline short f2bf(float f) {
  union { float f; unsigned u; } v; v.f = f;
  unsigned r = v.u + 0x7fffu + ((v.u >> 16) & 1u);
  return (short)(r >> 16);
}
__device__ inline unsigned fbits(float f) {
  union { float f; unsigned u; } v; v.f = f; return v.u;
}

__device__ inline void load_lds16(const short* g, short* l) {
  __builtin_amdgcn_global_load_lds((const __attribute__((address_space(1))) void*)g,
                                   (__attribute__((address_space(3))) void*)l, 16, 0, 0);
}

// fp32 -> bf16, 4 elems/thread.
__global__ __launch_bounds__(256) void cvt_f32_bf16(const float* __restrict__ in,
                                                    short* __restrict__ out, int n) {
  const int i = (blockIdx.x * 256 + threadIdx.x) * 4;
  if (i < n) {
    const float4 v = *(const float4*)(in + i);
    short4 o;
    o.x = f2bf(v.x); o.y = f2bf(v.y); o.z = f2bf(v.z); o.w = f2bf(v.w);
    *(short4*)(out + i) = o;
  }
}

// 4 weight matrices in one dispatch. grid (n/1024, 4).
__global__ __launch_bounds__(256) void cvt4_f32_bf16(const float* __restrict__ w0, const float* __restrict__ w1,
                                                     const float* __restrict__ w2, const float* __restrict__ w3,
                                                     short* __restrict__ o0, short* __restrict__ o1,
                                                     short* __restrict__ o2, short* __restrict__ o3, int n) {
  const float* in; short* out;
  switch (blockIdx.y) {
    case 0: in = w0; out = o0; break;
    case 1: in = w1; out = o1; break;
    case 2: in = w2; out = o2; break;
    default: in = w3; out = o3; break;
  }
  const int i = (blockIdx.x * 256 + threadIdx.x) * 4;
  if (i < n) {
    const float4 v = *(const float4*)(in + i);
    short4 o;
    o.x = f2bf(v.x); o.y = f2bf(v.y); o.z = f2bf(v.z); o.w = f2bf(v.w);
    *(short4*)(out + i) = o;
  }
}

// ---- BK=64 pipelined GEMM core ----------------------------------------
// LDS tile 128x64 bf16, row stride 128B, chunk-swizzled: slot (r,c) holds
// global 16B-chunk c^(r&7). Read: lane (quad,col) reading k-chunk ks*4+quad of
// row (..+col) uses slot chunk (ks*4+quad)^(col&7) -> per-quarter-wave banks
// spread 2/bank (floor). [BK=32's 64B rows were stuck at 2 start-banks/quad ->
// ~8-way conflict, 6.3M SQ_LDS_BANK_CONFLICT measured.]
// Staging: dest linear (wave base + lane*16B), source chunk pre-swizzled
// (rule: swizzle source + read, keep global_load_lds dest linear).
__device__ inline void stage_tile64(const short* __restrict__ g, int ld, int k0,
                                    short* l, int tid) {
  const int srow = tid >> 3;
  const int scol = (tid & 7) * 8;
  const int scg  = ((tid & 7) ^ ((tid >> 3) & 7)) * 8;
  for (int j = 0; j < 4; j++)
    load_lds16(&g[(size_t)(srow + j * 32) * ld + k0 + scg], &l[(srow + j * 32) * 64 + scol]);
}

__device__ inline void mfma_core64(const short* lA, const short* lB, int wm, int wn,
                                   int col, int quad, f32x4 acc[4][4]) {
  for (int ks = 0; ks < 2; ks++) {
    const int cs = ((ks * 4 + quad) ^ (col & 7)) * 8;
    bf16x8 af[4], bfr[4];
    for (int i = 0; i < 4; i++) af[i]  = *(const bf16x8*)&lA[(wm + i * 16 + col) * 64 + cs];
    for (int j = 0; j < 4; j++) bfr[j] = *(const bf16x8*)&lB[(wn + j * 16 + col) * 64 + cs];
    for (int i = 0; i < 4; i++)
      for (int j = 0; j < 4; j++)
        acc[i][j] = __builtin_amdgcn_mfma_f32_16x16x32_bf16(af[i], bfr[j], acc[i][j], 0, 0, 0);
  }
}

// Generic bf16 GEMM v2: BK=64, double-buffered LDS (64KB -> 2 blocks/CU),
// pipelined: stage(next) issued BEFORE compute(cur), ONE barrier per K-tile
// (drains vmcnt(0): next buffer ready; lgkm: cur reads done before overwrite).
// grid (M/128, N/128): m-block fast.
template <bool CF32>
__global__ __launch_bounds__(256) void gemm_bb(const short* __restrict__ A,
                                               const short* __restrict__ Bt,
                                               void* __restrict__ Cv,
                                               const float* __restrict__ bias,
                                               int M, int N, int K) {
  __shared__ __align__(16) short lA[2][128 * 64];
  __shared__ __align__(16) short lB[2][128 * 64];
  const int tid = threadIdx.x;
  const int wave = tid >> 6, lane = tid & 63;
  const int quad = lane >> 4, col = lane & 15;
  const int m0 = blockIdx.x * 128, n0 = blockIdx.y * 128;
  const int wm = (wave >> 1) * 64, wn = (wave & 1) * 64;

  f32x4 acc[4][4];
  for (int i = 0; i < 4; i++)
    for (int j = 0; j < 4; j++) acc[i][j] = (f32x4){0.f, 0.f, 0.f, 0.f};

  const int NT = K >> 6;
  stage_tile64(&A[(size_t)m0 * K], K, 0, lA[0], tid);
  stage_tile64(&Bt[(size_t)n0 * K], K, 0, lB[0], tid);
  __syncthreads();
  for (int kt = 0; kt < NT; kt++) {
    const int cur = kt & 1;
    if (kt + 1 < NT) {
      stage_tile64(&A[(size_t)m0 * K], K, (kt + 1) * 64, lA[cur ^ 1], tid);
      stage_tile64(&Bt[(size_t)n0 * K], K, (kt + 1) * 64, lB[cur ^ 1], tid);
    }
    mfma_core64(lA[cur], lB[cur], wm, wn, col, quad, acc);
    __syncthreads();
  }

  for (int j = 0; j < 4; j++) {
    const int gn = n0 + wn + j * 16 + col;
    const float bv = bias ? bias[gn] : 0.f;
    for (int i = 0; i < 4; i++) {
      const int gm = m0 + wm + i * 16 + quad * 4;
      for (int r = 0; r < 4; r++) {
        if (CF32) ((float*)Cv)[(size_t)(gm + r) * N + gn] = acc[i][j][r] + bv;
        else      ((short*)Cv)[(size_t)(gm + r) * N + gn] = f2bf(acc[i][j][r] + bv);
      }
    }
  }
}

// Fused Q/K/V projection v2 (same BK=64 pipelined core). grid (M/128, 24).
// Q output PRE-SCALED by 0.125*log2(e) so flash softmax is exp2(s) directly.
// Q,K dests token-major [8192][1024]; V dest TRANSPOSED per batch: vt[(b*1024+gn)*2048 + s].
__global__ __launch_bounds__(256) void gemm_qkv(const short* __restrict__ A,
                                                const short* Wq, const short* Wk, const short* Wv,
                                                short* Cq, short* Ck, short* Cvt) {
  __shared__ __align__(16) short lA[2][128 * 64];
  __shared__ __align__(16) short lB[2][128 * 64];
  const int nsel = blockIdx.y >> 3;
  const int n0 = (blockIdx.y & 7) * 128;
  const short* Bt = nsel == 0 ? Wq : (nsel == 1 ? Wk : Wv);
  const int tid = threadIdx.x;
  const int wave = tid >> 6, lane = tid & 63;
  const int quad = lane >> 4, col = lane & 15;
  const int m0 = blockIdx.x * 128;
  const int wm = (wave >> 1) * 64, wn = (wave & 1) * 64;
  const int K = D_, N = D_;

  f32x4 acc[4][4];
  for (int i = 0; i < 4; i++)
    for (int j = 0; j < 4; j++) acc[i][j] = (f32x4){0.f, 0.f, 0.f, 0.f};

  const int NT = K >> 6;
  stage_tile64(&A[(size_t)m0 * K], K, 0, lA[0], tid);
  stage_tile64(&Bt[(size_t)n0 * K], K, 0, lB[0], tid);
  __syncthreads();
  for (int kt = 0; kt < NT; kt++) {
    const int cur = kt & 1;
    if (kt + 1 < NT) {
      stage_tile64(&A[(size_t)m0 * K], K, (kt + 1) * 64, lA[cur ^ 1], tid);
      stage_tile64(&Bt[(size_t)n0 * K], K, (kt + 1) * 64, lB[cur ^ 1], tid);
    }
    mfma_core64(lA[cur], lB[cur], wm, wn, col, quad, acc);
    __syncthreads();
  }

  if (nsel < 2) {
    short* C = nsel ? Ck : Cq;
    const float sc = nsel == 0 ? 0.18033688f : 1.0f;  // 0.125 * log2(e)
    for (int j = 0; j < 4; j++) {
      const int gn = n0 + wn + j * 16 + col;
      for (int i = 0; i < 4; i++) {
        const int gm = m0 + wm + i * 16 + quad * 4;
        for (int r = 0; r < 4; r++)
          C[(size_t)(gm + r) * N + gn] = f2bf(acc[i][j][r] * sc);
      }
    }
  } else {
    for (int j = 0; j < 4; j++) {
      const int gn = n0 + wn + j * 16 + col;
      for (int i = 0; i < 4; i++) {
        const int gm = m0 + wm + i * 16 + quad * 4;
        const int bb = gm >> 11, s = gm & 2047;
        short4 o;
        o.x = f2bf(acc[i][j][0]); o.y = f2bf(acc[i][j][1]);
        o.z = f2bf(acc[i][j][2]); o.w = f2bf(acc[i][j][3]);
        *(short4*)&Cvt[((size_t)bb * D_ + gn) * (size_t)S_ + s] = o;
      }
    }
  }
}

// Flash attention v9: uniform pairing at 64-row q-slab granularity.
// grid (B*H, 16) = 1024 blocks (4/CU, the 40KB LDS limit); block y does slab
// 31-y then slab y -> (32-y)+(y+1) = 33 kv64-tiles per block, uniform.
// Verified r5: total 283->266, flash_attn6 out of top-5 (~74us est).
__global__ __launch_bounds__(256) void flash_attn6(const short* __restrict__ Q,
                                                   const short* __restrict__ Kt,
                                                   const short* __restrict__ Vt,
                                                   short* __restrict__ O) {
  __shared__ __align__(16) short lK[2][64 * 64];   // [kv][d], chunk-swizzled (16KB)
  __shared__ __align__(16) short lV[2][64 * 64];   // [d][kv], chunk-swizzled (16KB)
  __shared__ __align__(16) short pl[4][16 * 64];   // per-wave P subtile (8KB total)
  const int tid = threadIdx.x, wave = tid >> 6, lane = tid & 63;
  const int quad = lane >> 4, col = lane & 15;
  const int bh = blockIdx.x;
  const int b = bh >> 4, h = bh & 15;
  const size_t qkbase = (size_t)b * S_ * D_ + (size_t)h * HS_;
  const size_t vtbase = ((size_t)b * D_ + (size_t)h * HS_) * (size_t)S_;

  const int srow = tid >> 3;
  const int scg = (tid & 7) ^ (srow & 7);
  const int cs0 = (quad ^ (col & 7)) * 8;
  const int cs1 = ((quad + 4) ^ (col & 7)) * 8;
  short* plw = pl[wave];

  bf16x8 ones;
  for (int i = 0; i < 8; i++) ones[i] = (short)0x3F80;  // bf16 1.0

  int nb = 0;  // next-stage buffer parity, carried across halves

  for (int half = 0; half < 2; half++) {
    const int s = half ? (int)blockIdx.y : 31 - (int)blockIdx.y;  // heavy first
    const int qmin = s * 64 + wave * 16;           // wave owns q rows qmin..qmin+15
    const int L = s;                               // kv64 tiles 0..L

    // stage tile 0 into buf nb (not read since the last barrier)
    load_lds16(&Kt[qkbase + (size_t)srow * D_ + scg * 8],        &lK[nb][tid * 8]);
    load_lds16(&Kt[qkbase + (size_t)(32 + srow) * D_ + scg * 8], &lK[nb][2048 + tid * 8]);
    load_lds16(&Vt[vtbase + (size_t)srow * S_ + scg * 8],        &lV[nb][tid * 8]);
    load_lds16(&Vt[vtbase + (size_t)(srow + 32) * S_ + scg * 8], &lV[nb][2048 + tid * 8]);
    const int cur0 = nb;
    nb ^= 1;

    bf16x8 qf[2];
    for (int x = 0; x < 2; x++)
      qf[x] = *(const bf16x8*)&Q[qkbase + (size_t)(qmin + col) * D_ + x * 32 + quad * 8];

    f32x4 oacc[4], lacc;
    for (int dt = 0; dt < 4; dt++) oacc[dt] = (f32x4){0.f, 0.f, 0.f, 0.f};
    lacc = (f32x4){0.f, 0.f, 0.f, 0.f};

    for (int nt = 0; nt <= L; nt++) {
      const int n0 = nt * 64;
      const int cur = cur0 ^ (nt & 1);
      __syncthreads();  // drains staging for cur; all waves past prior reads
      if (nt < L) {
        const int nn = n0 + 64;  // nb == cur^1 here (invariant)
        load_lds16(&Kt[qkbase + (size_t)(nn + srow) * D_ + scg * 8],      &lK[nb][tid * 8]);
        load_lds16(&Kt[qkbase + (size_t)(nn + 32 + srow) * D_ + scg * 8], &lK[nb][2048 + tid * 8]);
        load_lds16(&Vt[vtbase + (size_t)srow * S_ + nn + scg * 8],        &lV[nb][tid * 8]);
        load_lds16(&Vt[vtbase + (size_t)(srow + 32) * S_ + nn + scg * 8], &lV[nb][2048 + tid * 8]);
        nb ^= 1;
      }

      const short* lKc = lK[cur];
      const short* lVc = lV[cur];
      const bool needM = (nt == L);  // only the diagonal tile masks

      // K A-fragments
      bf16x8 kf[4][2];
      for (int t = 0; t < 4; t++) {
        const int rb = (t * 16 + col) * 64;
        kf[t][0] = *(const bf16x8*)&lKc[rb + cs0];
        kf[t][1] = *(const bf16x8*)&lKc[rb + cs1];
      }

      const int qg = qmin + col;  // this lane's q row
      // S^T = K * Q^T: lane holds 4 kv-consecutive values per t-tile
      for (int t = 0; t < 4; t++) {
        f32x4 z = (f32x4){0.f, 0.f, 0.f, 0.f};
        __builtin_amdgcn_s_setprio(1);
        z = __builtin_amdgcn_mfma_f32_16x16x32_bf16(kf[t][0], qf[0], z, 0, 0, 0);
        z = __builtin_amdgcn_mfma_f32_16x16x32_bf16(kf[t][1], qf[1], z, 0, 0, 0);
        __builtin_amdgcn_s_setprio(0);
        float p0 = exp2f(z[0]);
        float p1 = exp2f(z[1]);
        float p2 = exp2f(z[2]);
        float p3 = exp2f(z[3]);
        if (needM) {
          const int kv = n0 + t * 16 + quad * 4;
          if (kv + 0 > qg) p0 = 0.f;
          if (kv + 1 > qg) p1 = 0.f;
          if (kv + 2 > qg) p2 = 0.f;
          if (kv + 3 > qg) p3 = 0.f;
        }
        // truncation-pack two bf16 per dword via v_perm (bias cancels in ratio)
        unsigned d0 = __builtin_amdgcn_perm(fbits(p1), fbits(p0), 0x07060302u);
        unsigned d1 = __builtin_amdgcn_perm(fbits(p3), fbits(p2), 0x07060302u);
        const int cc = (2 * t + (quad >> 1)) ^ (col & 7);
        uint2 w; w.x = d0; w.y = d1;
        *(uint2*)&plw[col * 64 + cc * 8 + (quad & 1) * 4] = w;
      }

      // PV + row-sum (wave-coherent ds_write -> lgkmcnt -> ds_read, no barrier)
      for (int h2 = 0; h2 < 2; h2++) {
        const int cgo = ((h2 * 4 + quad) ^ (col & 7)) * 8;
        const bf16x8 pf = *(const bf16x8*)&plw[col * 64 + cgo];
        bf16x8 vf[4];
        for (int dt = 0; dt < 4; dt++)
          vf[dt] = *(const bf16x8*)&lVc[(dt * 16 + col) * 64 + cgo];
        __builtin_amdgcn_s_setprio(1);
        lacc = __builtin_amdgcn_mfma_f32_16x16x32_bf16(pf, ones, lacc, 0, 0, 0);
        for (int dt = 0; dt < 4; dt++)
          oacc[dt] = __builtin_amdgcn_mfma_f32_16x16x32_bf16(pf, vf[dt], oacc[dt], 0, 0, 0);
        __builtin_amdgcn_s_setprio(0);
      }
    }

    for (int r = 0; r < 4; r++) {
      const float inv = 1.f / lacc[r];
      const size_t row = qkbase + (size_t)(qmin + quad * 4 + r) * D_;
      for (int dt = 0; dt < 4; dt++)
        O[row + dt * 16 + col] = f2bf(oacc[dt][r] * inv);
    }
  }
}

// ---- legacy fallback kernels (small-ws paths) ----
__global__ __launch_bounds__(256) void gemm_ff(const float* __restrict__ A,
                                               const float* __restrict__ Bt,
                                               short* __restrict__ C,
                                               int M, int N, int K) {
  __shared__ __align__(16) short lA[128 * 32];
  __shared__ __align__(16) short lB[128 * 32];
  const int tid = threadIdx.x;
  const int wave = tid >> 6, lane = tid & 63;
  const int quad = lane >> 4, col = lane & 15;
  const int m0 = blockIdx.y * 128, n0 = blockIdx.x * 128;
  const int wm = (wave >> 1) * 64, wn = (wave & 1) * 64;
  const int srow2 = tid >> 1;
  const int sc = (tid & 1) * 16;

  f32x4 acc[4][4];
  for (int i = 0; i < 4; i++)
    for (int j = 0; j < 4; j++) acc[i][j] = (f32x4){0.f, 0.f, 0.f, 0.f};

  for (int k0 = 0; k0 < K; k0 += 32) {
    __syncthreads();
    {
      const float4* ga = (const float4*)&A[(size_t)(m0 + srow2) * K + k0 + sc];
      const float4 v0 = ga[0], v1 = ga[1], v2 = ga[2], v3 = ga[3];
      bf16x8 p0, p1;
      p0[0] = f2bf(v0.x); p0[1] = f2bf(v0.y); p0[2] = f2bf(v0.z); p0[3] = f2bf(v0.w);
      p0[4] = f2bf(v1.x); p0[5] = f2bf(v1.y); p0[6] = f2bf(v1.z); p0[7] = f2bf(v1.w);
      p1[0] = f2bf(v2.x); p1[1] = f2bf(v2.y); p1[2] = f2bf(v2.z); p1[3] = f2bf(v2.w);
      p1[4] = f2bf(v3.x); p1[5] = f2bf(v3.y); p1[6] = f2bf(v3.z); p1[7] = f2bf(v3.w);
      *(bf16x8*)&lA[srow2 * 32 + sc]     = p0;
      *(bf16x8*)&lA[srow2 * 32 + sc + 8] = p1;
    }
    {
      const float4* gb = (const float4*)&Bt[(size_t)(n0 + srow2) * K + k0 + sc];
      const float4 v0 = gb[0], v1 = gb[1], v2 = gb[2], v3 = gb[3];
      bf16x8 p0, p1;
      p0[0] = f2bf(v0.x); p0[1] = f2bf(v0.y); p0[2] = f2bf(v0.z); p0[3] = f2bf(v0.w);
      p0[4] = f2bf(v1.x); p0[5] = f2bf(v1.y); p0[6] = f2bf(v1.z); p0[7] = f2bf(v1.w);
      p1[0] = f2bf(v2.x); p1[1] = f2bf(v2.y); p1[2] = f2bf(v2.z); p1[3] = f2bf(v2.w);
      p1[4] = f2bf(v3.x); p1[5] = f2bf(v3.y); p1[6] = f2bf(v3.z); p1[7] = f2bf(v3.w);
      *(bf16x8*)&lB[srow2 * 32 + sc]     = p0;
      *(bf16x8*)&lB[srow2 * 32 + sc + 8] = p1;
    }
    __syncthreads();
    {
      bf16x8 af[4], bfr[4];
      for (int i = 0; i < 4; i++) af[i]  = *(const bf16x8*)&lA[(wm + i * 16 + col) * 32 + quad * 8];
      for (int j = 0; j < 4; j++) bfr[j] = *(const bf16x8*)&lB[(wn + j * 16 + col) * 32 + quad * 8];
      for (int i = 0; i < 4; i++)
        for (int j = 0; j < 4; j++)
          acc[i][j] = __builtin_amdgcn_mfma_f32_16x16x32_bf16(af[i], bfr[j], acc[i][j], 0, 0, 0);
    }
  }

  for (int j = 0; j < 4; j++) {
    const int gn = n0 + wn + j * 16 + col;
    for (int i = 0; i < 4; i++) {
      const int gm = m0 + wm + i * 16 + quad * 4;
      for (int r = 0; r < 4; r++)
        C[(size_t)(gm + r) * N + gn] = f2bf(acc[i][j][r]);
    }
  }
}

__global__ __launch_bounds__(256) void gemm_out_bf(const short* __restrict__ A,
                                                   const float* __restrict__ Bt,
                                                   float* __restrict__ C,
                                                   const float* __restrict__ bias,
                                                   int M, int N, int K) {
  __shared__ __align__(16) short lA[128 * 32];
  __shared__ __align__(16) short lB[128 * 32];
  const int tid = threadIdx.x;
  const int wave = tid >> 6, lane = tid & 63;
  const int quad = lane >> 4, col = lane & 15;
  const int m0 = blockIdx.y * 128, n0 = blockIdx.x * 128;
  const int wm = (wave >> 1) * 64, wn = (wave & 1) * 64;
  const int srow = wave * 32 + (lane >> 2);
  const int scol = (lane & 3) * 8;
  const int srow2 = tid >> 1;
  const int sc = (tid & 1) * 16;

  f32x4 acc[4][4];
  for (int i = 0; i < 4; i++)
    for (int j = 0; j < 4; j++) acc[i][j] = (f32x4){0.f, 0.f, 0.f, 0.f};

  for (int k0 = 0; k0 < K; k0 += 32) {
    __syncthreads();
    load_lds16(&A[(size_t)(m0 + srow) * K + k0 + scol],      &lA[srow * 32 + scol]);
    load_lds16(&A[(size_t)(m0 + srow + 16) * K + k0 + scol], &lA[(srow + 16) * 32 + scol]);
    {
      const float4* gb = (const float4*)&Bt[(size_t)(n0 + srow2) * K + k0 + sc];
      const float4 v0 = gb[0], v1 = gb[1], v2 = gb[2], v3 = gb[3];
      bf16x8 p0, p1;
      p0[0] = f2bf(v0.x); p0[1] = f2bf(v0.y); p0[2] = f2bf(v0.z); p0[3] = f2bf(v0.w);
      p0[4] = f2bf(v1.x); p0[5] = f2bf(v1.y); p0[6] = f2bf(v1.z); p0[7] = f2bf(v1.w);
      p1[0] = f2bf(v2.x); p1[1] = f2bf(v2.y); p1[2] = f2bf(v2.z); p1[3] = f2bf(v2.w);
      p1[4] = f2bf(v3.x); p1[5] = f2bf(v3.y); p1[6] = f2bf(v3.z); p1[7] = f2bf(v3.w);
      *(bf16x8*)&lB[srow2 * 32 + sc]     = p0;
      *(bf16x8*)&lB[srow2 * 32 + sc + 8] = p1;
    }
    __syncthreads();
    {
      bf16x8 af[4], bfr[4];
      for (int i = 0; i < 4; i++) af[i]  = *(const bf16x8*)&lA[(wm + i * 16 + col) * 32 + quad * 8];
      for (int j = 0; j < 4; j++) bfr[j] = *(const bf16x8*)&lB[(wn + j * 16 + col) * 32 + quad * 8];
      for (int i = 0; i < 4; i++)
        for (int j = 0; j < 4; j++)
          acc[i][j] = __builtin_amdgcn_mfma_f32_16x16x32_bf16(af[i], bfr[j], acc[i][j], 0, 0, 0);
    }
  }

  for (int j = 0; j < 4; j++) {
    const int gn = n0 + wn + j * 16 + col;
    const float bv = bias ? bias[gn] : 0.f;
    for (int i = 0; i < 4; i++) {
      const int gm = m0 + wm + i * 16 + quad * 4;
      for (int r = 0; r < 4; r++)
        C[(size_t)(gm + r) * N + gn] = acc[i][j][r] + bv;
    }
  }
}

__global__ __launch_bounds__(64) void flash_attn(const short* __restrict__ Q,
                                                 const short* __restrict__ K,
                                                 const short* __restrict__ V,
                                                 short* __restrict__ O) {
  __shared__ __align__(16) short pl[16 * 40];
  const int lane = threadIdx.x;
  const int quad = lane >> 4, col = lane & 15;
  const int blk = blockIdx.x;
  const int qt = blk & 127;
  const int bh = blk >> 7;
  const int b = bh >> 4, h = bh & 15;
  const int q0 = qt * 16;
  const size_t base = (size_t)b * S_ * D_ + (size_t)h * HS_;

  const bf16x8 qf0 = *(const bf16x8*)&Q[base + (size_t)(q0 + col) * D_ + quad * 8];
  const bf16x8 qf1 = *(const bf16x8*)&Q[base + (size_t)(q0 + col) * D_ + 32 + quad * 8];

  float mr[4], lr[4];
  f32x4 oacc[4];
  for (int r = 0; r < 4; r++) { mr[r] = -1e30f; lr[r] = 0.f; }
  for (int dt = 0; dt < 4; dt++) oacc[dt] = (f32x4){0.f, 0.f, 0.f, 0.f};

  const int ntiles = (q0 + 15) / 32 + 1;
  for (int nt = 0; nt < ntiles; nt++) {
    const int n0 = nt * 32;
    f32x4 s[2];
    s[0] = (f32x4){0.f, 0.f, 0.f, 0.f};
    s[1] = (f32x4){0.f, 0.f, 0.f, 0.f};
    for (int t = 0; t < 2; t++) {
      const short* kp = &K[base + (size_t)(n0 + t * 16 + col) * D_ + quad * 8];
      const bf16x8 kf0 = *(const bf16x8*)kp;
      const bf16x8 kf1 = *(const bf16x8*)(kp + 32);
      s[t] = __builtin_amdgcn_mfma_f32_16x16x32_bf16(qf0, kf0, s[t], 0, 0, 0);
      s[t] = __builtin_amdgcn_mfma_f32_16x16x32_bf16(qf1, kf1, s[t], 0, 0, 0);
    }
    for (int r = 0; r < 4; r++) {
      const int mg = q0 + quad * 4 + r;
      float s0 = s[0][r] * 0.125f; if (n0 + col > mg)      s0 = -1e30f;
      float s1 = s[1][r] * 0.125f; if (n0 + 16 + col > mg) s1 = -1e30f;
      float tm = fmaxf(s0, s1);
      for (int off = 1; off < 16; off <<= 1) tm = fmaxf(tm, __shfl_xor(tm, off));
      const float mnew = fmaxf(mr[r], tm);
      const float alpha = __expf(mr[r] - mnew);
      mr[r] = mnew;
      const float p0 = __expf(s0 - mnew);
      const float p1 = __expf(s1 - mnew);
      float ps = p0 + p1;
      for (int off = 1; off < 16; off <<= 1) ps += __shfl_xor(ps, off);
      lr[r] = lr[r] * alpha + ps;
      for (int dt = 0; dt < 4; dt++) oacc[dt][r] *= alpha;
      pl[(quad * 4 + r) * 40 + col]      = f2bf(p0);
      pl[(quad * 4 + r) * 40 + 16 + col] = f2bf(p1);
    }
    const bf16x8 pf = *(const bf16x8*)&pl[col * 40 + quad * 8];
    for (int dt = 0; dt < 4; dt++) {
      bf16x8 vf;
      const short* vp = &V[base + (size_t)(n0 + quad * 8) * D_ + dt * 16 + col];
      for (int j = 0; j < 8; j++) vf[j] = vp[(size_t)j * D_];
      oacc[dt] = __builtin_amdgcn_mfma_f32_16x16x32_bf16(pf, vf, oacc[dt], 0, 0, 0);
    }
  }

  for (int r = 0; r < 4; r++) {
    const float inv = 1.f / lr[r];
    const size_t row = base + (size_t)(q0 + quad * 4 + r) * D_;
    for (int dt = 0; dt < 4; dt++)
      O[row + dt * 16 + col] = f2bf(oacc[dt][r] * inv);
  }
}

extern "C" void kernel_launch(void* const* d_in, const int* in_sizes, int n_in,
                              void* d_out, int out_size, void* d_ws, size_t ws_size,
                              hipStream_t stream) {
  const float* x  = (const float*)d_in[0];
  const float* Wk = (const float*)d_in[1];
  const float* Wq = (const float*)d_in[2];
  const float* Wv = (const float*)d_in[3];
  const float* Wo = (const float*)d_in[4];
  const float* bo = (const float*)d_in[5];
  float* out = (float*)d_out;

  char* ws = (char*)d_ws;
  const size_t MiB = 1u << 20;
  const int M = B_ * S_, N = D_, K = D_;
  const int nx = M * D_, nw = D_ * D_;

  if (ws_size >= 88 * MiB) {
    short* xb    = (short*)(ws);
    short* wkb   = (short*)(ws + 16 * MiB);
    short* wqb   = (short*)(ws + 18 * MiB);
    short* wvb   = (short*)(ws + 20 * MiB);
    short* wob   = (short*)(ws + 22 * MiB);
    short* q_ws  = (short*)(ws + 24 * MiB);
    short* k_ws  = (short*)(ws + 40 * MiB);
    short* vt_ws = (short*)(ws + 56 * MiB);
    short* a_ws  = (short*)(ws + 72 * MiB);

    hipLaunchKernelGGL(cvt_f32_bf16, dim3(nx / 1024), dim3(256), 0, stream, x, xb, nx);
    hipLaunchKernelGGL(cvt4_f32_bf16, dim3(nw / 1024, 4), dim3(256), 0, stream,
                       Wq, Wk, Wv, Wo, wqb, wkb, wvb, wob, nw);
    hipLaunchKernelGGL(gemm_qkv, dim3(M / 128, 24), dim3(256), 0, stream,
                       xb, wqb, wkb, wvb, q_ws, k_ws, vt_ws);
    hipLaunchKernelGGL(flash_attn6, dim3(B_ * H_, 16), dim3(256), 0, stream,
                       q_ws, k_ws, vt_ws, a_ws);
    hipLaunchKernelGGL((gemm_bb<true>), dim3(M / 128, N / 128), dim3(256), 0, stream,
                       a_ws, wob, (void*)out, bo, M, N, K);
  } else if (ws_size >= 64 * MiB) {
    short* q_ws = (short*)(ws);
    short* k_ws = (short*)(ws + 16 * MiB);
    short* v_ws = (short*)(ws + 32 * MiB);
    short* a_ws = (short*)(ws + 48 * MiB);
    dim3 gg(N / 128, M / 128), gb(256);
    hipLaunchKernelGGL(gemm_ff, gg, gb, 0, stream, x, Wq, q_ws, M, N, K);
    hipLaunchKernelGGL(gemm_ff, gg, gb, 0, stream, x, Wk, k_ws, M, N, K);
    hipLaunchKernelGGL(gemm_ff, gg, gb, 0, stream, x, Wv, v_ws, M, N, K);
    hipLaunchKernelGGL(flash_attn, dim3(B_ * H_ * (S_ / 16)), dim3(64), 0, stream, q_ws, k_ws, v_ws, a_ws);
    hipLaunchKernelGGL(gemm_out_bf, gg, gb, 0, stream, a_ws, Wo, out, bo, M, N, K);
  } else {
    short* q_ws = (short*)(ws);
    short* k_ws = (short*)(ws + 4 * MiB);
    short* v_ws = (short*)(ws + 8 * MiB);
    short* a_ws = (short*)(ws + 12 * MiB);
    const int Mb = S_;
    dim3 gg(N / 128, Mb / 128), gb(256);
    for (int b = 0; b < B_; b++) {
      const float* xb = x + (size_t)b * S_ * D_;
      float* ob = out + (size_t)b * S_ * D_;
      hipLaunchKernelGGL(gemm_ff, gg, gb, 0, stream, xb, Wq, q_ws, Mb, N, K);
      hipLaunchKernelGGL(gemm_ff, gg, gb, 0, stream, xb, Wk, k_ws, Mb, N, K);
      hipLaunchKernelGGL(gemm_ff, gg, gb, 0, stream, xb, Wv, v_ws, Mb, N, K);
      hipLaunchKernelGGL(flash_attn, dim3(H_ * (S_ / 16)), dim3(64), 0, stream, q_ws, k_ws, v_ws, a_ws);
      hipLaunchKernelGGL(gemm_out_bf, gg, gb, 0, stream, a_ws, Wo, ob, bo, Mb, N, K);
    }
  }
}

// Round 8
// 256.877 us; speedup vs baseline: 1.0408x; 1.0408x over previous
//
#include <hip/hip_runtime.h>

#define B_ 4
#define S_ 2048
#define D_ 1024
#define H_ 16
#define HS_ 64

typedef float f32x4 __attribute__((ext_vector_type(4)));
typedef short bf16x8 __attribute__((ext_vector_type(8)));

__device__ inline short f2bf(float f) {
  union { float f; unsigned u; } v; v.f = f;
  unsigned r = v.u + 0x7fffu + ((v.u >> 16) & 1u);
  return (short)(r >> 16);
}
__device__ inline unsigned fbits(float f) {
  union { float f; unsigned u; } v; v.f = f; return v.u;
}

__device__ inline void load_lds16(const short* g, short* l) {
  __builtin_amdgcn_global_load_lds((const __attribute__((address_space(1))) void*)g,
                                   (__attribute__((address_space(3))) void*)l, 16, 0, 0);
}

// fp32 -> bf16, 4 elems/thread.
__global__ __launch_bounds__(256) void cvt_f32_bf16(const float* __restrict__ in,
                                                    short* __restrict__ out, int n) {
  const int i = (blockIdx.x * 256 + threadIdx.x) * 4;
  if (i < n) {
    const float4 v = *(const float4*)(in + i);
    short4 o;
    o.x = f2bf(v.x); o.y = f2bf(v.y); o.z = f2bf(v.z); o.w = f2bf(v.w);
    *(short4*)(out + i) = o;
  }
}

// 4 weight matrices in one dispatch. grid (n/1024, 4).
__global__ __launch_bounds__(256) void cvt4_f32_bf16(const float* __restrict__ w0, const float* __restrict__ w1,
                                                     const float* __restrict__ w2, const float* __restrict__ w3,
                                                     short* __restrict__ o0, short* __restrict__ o1,
                                                     short* __restrict__ o2, short* __restrict__ o3, int n) {
  const float* in; short* out;
  switch (blockIdx.y) {
    case 0: in = w0; out = o0; break;
    case 1: in = w1; out = o1; break;
    case 2: in = w2; out = o2; break;
    default: in = w3; out = o3; break;
  }
  const int i = (blockIdx.x * 256 + threadIdx.x) * 4;
  if (i < n) {
    const float4 v = *(const float4*)(in + i);
    short4 o;
    o.x = f2bf(v.x); o.y = f2bf(v.y); o.z = f2bf(v.z); o.w = f2bf(v.w);
    *(short4*)(out + i) = o;
  }
}

// ---- BK=64 pipelined GEMM core (128^2, 2-phase) -----------------------
__device__ inline void stage_tile64(const short* __restrict__ g, int ld, int k0,
                                    short* l, int tid) {
  const int srow = tid >> 3;
  const int scol = (tid & 7) * 8;
  const int scg  = ((tid & 7) ^ ((tid >> 3) & 7)) * 8;
  for (int j = 0; j < 4; j++)
    load_lds16(&g[(size_t)(srow + j * 32) * ld + k0 + scg], &l[(srow + j * 32) * 64 + scol]);
}

__device__ inline void mfma_core64(const short* lA, const short* lB, int wm, int wn,
                                   int col, int quad, f32x4 acc[4][4]) {
  for (int ks = 0; ks < 2; ks++) {
    const int cs = ((ks * 4 + quad) ^ (col & 7)) * 8;
    bf16x8 af[4], bfr[4];
    for (int i = 0; i < 4; i++) af[i]  = *(const bf16x8*)&lA[(wm + i * 16 + col) * 64 + cs];
    for (int j = 0; j < 4; j++) bfr[j] = *(const bf16x8*)&lB[(wn + j * 16 + col) * 64 + cs];
    for (int i = 0; i < 4; i++)
      for (int j = 0; j < 4; j++)
        acc[i][j] = __builtin_amdgcn_mfma_f32_16x16x32_bf16(af[i], bfr[j], acc[i][j], 0, 0, 0);
  }
}

// Generic bf16 GEMM (r6 structure kept): BK=64, dbuf, 2-phase. grid (M/128, N/128).
template <bool CF32>
__global__ __launch_bounds__(256) void gemm_bb(const short* __restrict__ A,
                                               const short* __restrict__ Bt,
                                               void* __restrict__ Cv,
                                               const float* __restrict__ bias,
                                               int M, int N, int K) {
  __shared__ __align__(16) short lA[2][128 * 64];
  __shared__ __align__(16) short lB[2][128 * 64];
  const int tid = threadIdx.x;
  const int wave = tid >> 6, lane = tid & 63;
  const int quad = lane >> 4, col = lane & 15;
  const int m0 = blockIdx.x * 128, n0 = blockIdx.y * 128;
  const int wm = (wave >> 1) * 64, wn = (wave & 1) * 64;

  f32x4 acc[4][4];
  for (int i = 0; i < 4; i++)
    for (int j = 0; j < 4; j++) acc[i][j] = (f32x4){0.f, 0.f, 0.f, 0.f};

  const int NT = K >> 6;
  stage_tile64(&A[(size_t)m0 * K], K, 0, lA[0], tid);
  stage_tile64(&Bt[(size_t)n0 * K], K, 0, lB[0], tid);
  __syncthreads();
  for (int kt = 0; kt < NT; kt++) {
    const int cur = kt & 1;
    if (kt + 1 < NT) {
      stage_tile64(&A[(size_t)m0 * K], K, (kt + 1) * 64, lA[cur ^ 1], tid);
      stage_tile64(&Bt[(size_t)n0 * K], K, (kt + 1) * 64, lB[cur ^ 1], tid);
    }
    mfma_core64(lA[cur], lB[cur], wm, wn, col, quad, acc);
    __syncthreads();
  }

  for (int j = 0; j < 4; j++) {
    const int gn = n0 + wn + j * 16 + col;
    const float bv = bias ? bias[gn] : 0.f;
    for (int i = 0; i < 4; i++) {
      const int gm = m0 + wm + i * 16 + quad * 4;
      for (int r = 0; r < 4; r++) {
        if (CF32) ((float*)Cv)[(size_t)(gm + r) * N + gn] = acc[i][j][r] + bv;
        else      ((short*)Cv)[(size_t)(gm + r) * N + gn] = f2bf(acc[i][j][r] + bv);
      }
    }
  }
}

// ---- Fused Q/K/V projection, 256^2 8-phase schedule (T2+T3+T4+T5) -----
// BM=BN=256, BK=64, 8 waves (2M x 4N), wave tile 128x64, LDS 128KB
// (2 dbuf x [A 256x64 + B 256x64]). 512 threads, 1 block/CU.
// Per K-tile: 4 phases, each {ds_read subtile; stage 1 region; s_barrier;
// lgkmcnt(0); setprio(1); 16 MFMA; setprio(0); s_barrier}.
// 2-tile lookahead with IN-PLACE region staging: tile t+2 staged into
// buf[t&1] regions already consumed this tile. Read-completion map:
//   ph p reads A rows {32p..+31} u {128+32p..+31} (region R_p); B all at ph0.
// Stage ledger (8 loads/tile, 1 per region, 512thr x 16B = 8KB = 1 region):
//   ph0: A-R3(t+1)->buf[t^1] (not read during t); ph1: B-q0,q1(t+2);
//   ph2: B-q2,q3(t+2); ph3: A-R0,R1,R2(t+2) (freed ph0/1/2).
// Gate: vmcnt(7) at ph3 (7 loads newer than tile t+1's last) -> tile t+1
// fully landed; NEVER vmcnt(0) in steady state (the T4 mechanism).
// Swizzle: same chunk-XOR involution as r6 (slot c holds global chunk
// c^(row&7)); verified conflict-free (r6: 6.3M -> 0).
__global__ __launch_bounds__(512, 2) void gemm_qkv8(const short* __restrict__ A,
                                                    const short* Wq, const short* Wk, const short* Wv,
                                                    short* Cq, short* Ck, short* Cvt) {
  __shared__ __align__(16) short lds[2][2][256 * 64];  // [buf][A/B][...]
  const int tid = threadIdx.x;
  const int wave = tid >> 6, lane = tid & 63;
  const int quad = lane >> 4, col = lane & 15;
  const int nsel = blockIdx.y >> 2;
  const int n0 = (blockIdx.y & 3) * 256;
  const short* Bt = nsel == 0 ? Wq : (nsel == 1 ? Wk : Wv);
  const int m0 = blockIdx.x * 256;
  const int wm = (wave >> 2) * 128, wn = (wave & 3) * 64;
  const int K = D_;
  const int NT = 16;  // K/64

  const int srow_base = ((tid >> 3) & 31) + ((tid >> 8) << 7);  // +32p per region
  const int sc8 = tid & 7;
  const short* gA = &A[(size_t)m0 * K];
  const short* gB = &Bt[(size_t)n0 * K];

  auto stageA = [&](int t, int p) {
    const int row = p * 32 + srow_base;
    load_lds16(&gA[(size_t)row * K + t * 64 + ((sc8 ^ (row & 7)) * 8)],
               &lds[t & 1][0][row * 64 + sc8 * 8]);
  };
  auto stageB = [&](int t, int p) {
    const int row = p * 32 + srow_base;
    load_lds16(&gB[(size_t)row * K + t * 64 + ((sc8 ^ (row & 7)) * 8)],
               &lds[t & 1][1][row * 64 + sc8 * 8]);
  };

  f32x4 acc[8][4];
#pragma unroll
  for (int f = 0; f < 8; f++)
#pragma unroll
    for (int j = 0; j < 4; j++) acc[f][j] = (f32x4){0.f, 0.f, 0.f, 0.f};

  // Prologue ledger: tile0 (8 loads, oldest), tile1 (7: B q0-3, A R0-2).
  for (int p = 0; p < 4; p++) stageA(0, p);
  for (int p = 0; p < 4; p++) stageB(0, p);
  for (int p = 0; p < 4; p++) stageB(1, p);
  for (int p = 0; p < 3; p++) stageA(1, p);
  asm volatile("s_waitcnt vmcnt(7)" ::: "memory");  // tile0's 8 landed
  __builtin_amdgcn_sched_barrier(0);
  __builtin_amdgcn_s_barrier();

  bf16x8 bfr[4][2];
  for (int t = 0; t < NT; t++) {
    const short* la = lds[t & 1][0];
    const short* lb = lds[t & 1][1];

#define QKV_PHASE(P, STAGES, GATE)                                                     \
    {                                                                                  \
      bf16x8 af[2][2];                                                                 \
      if (P == 0) {                                                                    \
        _Pragma("unroll")                                                              \
        for (int j = 0; j < 4; j++)                                                    \
          _Pragma("unroll")                                                            \
          for (int kk = 0; kk < 2; kk++)                                               \
            bfr[j][kk] = *(const bf16x8*)&lb[(wn + j * 16 + col) * 64 +                \
                                             (((kk * 4 + quad) ^ (col & 7)) * 8)];     \
      }                                                                                \
      _Pragma("unroll")                                                                \
      for (int f = 0; f < 2; f++)                                                      \
        _Pragma("unroll")                                                              \
        for (int kk = 0; kk < 2; kk++)                                                 \
          af[f][kk] = *(const bf16x8*)&la[(wm + (P * 2 + f) * 16 + col) * 64 +         \
                                          (((kk * 4 + quad) ^ (col & 7)) * 8)];        \
      STAGES                                                                           \
      __builtin_amdgcn_sched_barrier(0);                                               \
      __builtin_amdgcn_s_barrier();                                                    \
      asm volatile("s_waitcnt lgkmcnt(0)" ::: "memory");                               \
      __builtin_amdgcn_sched_barrier(0);                                               \
      __builtin_amdgcn_s_setprio(1);                                                   \
      _Pragma("unroll")                                                                \
      for (int f = 0; f < 2; f++)                                                      \
        _Pragma("unroll")                                                              \
        for (int j = 0; j < 4; j++)                                                    \
          _Pragma("unroll")                                                            \
          for (int kk = 0; kk < 2; kk++)                                               \
            acc[P * 2 + f][j] = __builtin_amdgcn_mfma_f32_16x16x32_bf16(               \
                af[f][kk], bfr[j][kk], acc[P * 2 + f][j], 0, 0, 0);                    \
      __builtin_amdgcn_s_setprio(0);                                                   \
      GATE                                                                             \
      __builtin_amdgcn_sched_barrier(0);                                               \
      __builtin_amdgcn_s_barrier();                                                    \
    }

    QKV_PHASE(0, { if (t + 1 < NT) stageA(t + 1, 3); }, {})
    QKV_PHASE(1, { if (t + 2 < NT) { stageB(t + 2, 0); stageB(t + 2, 1); } }, {})
    QKV_PHASE(2, { if (t + 2 < NT) { stageB(t + 2, 2); stageB(t + 2, 3); } }, {})
    QKV_PHASE(3, { if (t + 2 < NT) { stageA(t + 2, 0); stageA(t + 2, 1); stageA(t + 2, 2); } },
              {
                if (t + 2 < NT)      { asm volatile("s_waitcnt vmcnt(7)" ::: "memory"); }
                else if (t + 1 < NT) { asm volatile("s_waitcnt vmcnt(0)" ::: "memory"); }
              })
#undef QKV_PHASE
  }

  if (nsel < 2) {
    short* C = nsel ? Ck : Cq;
    const float sc = nsel == 0 ? 0.18033688f : 1.0f;  // 0.125 * log2(e)
    for (int j = 0; j < 4; j++) {
      const int gn = n0 + wn + j * 16 + col;
      for (int f = 0; f < 8; f++) {
        const int gm = m0 + wm + f * 16 + quad * 4;
        for (int r = 0; r < 4; r++)
          C[(size_t)(gm + r) * D_ + gn] = f2bf(acc[f][j][r] * sc);
      }
    }
  } else {
    for (int j = 0; j < 4; j++) {
      const int gn = n0 + wn + j * 16 + col;
      for (int f = 0; f < 8; f++) {
        const int gm = m0 + wm + f * 16 + quad * 4;
        const int bb = gm >> 11, s = gm & 2047;
        short4 o;
        o.x = f2bf(acc[f][j][0]); o.y = f2bf(acc[f][j][1]);
        o.z = f2bf(acc[f][j][2]); o.w = f2bf(acc[f][j][3]);
        *(short4*)&Cvt[((size_t)bb * D_ + gn) * (size_t)S_ + s] = o;
      }
    }
  }
}

// Flash attention v9: uniform pairing at 64-row q-slab granularity.
// Verified r5: total 283->266, flash_attn6 out of top-5 (~74us est).
__global__ __launch_bounds__(256) void flash_attn6(const short* __restrict__ Q,
                                                   const short* __restrict__ Kt,
                                                   const short* __restrict__ Vt,
                                                   short* __restrict__ O) {
  __shared__ __align__(16) short lK[2][64 * 64];
  __shared__ __align__(16) short lV[2][64 * 64];
  __shared__ __align__(16) short pl[4][16 * 64];
  const int tid = threadIdx.x, wave = tid >> 6, lane = tid & 63;
  const int quad = lane >> 4, col = lane & 15;
  const int bh = blockIdx.x;
  const int b = bh >> 4, h = bh & 15;
  const size_t qkbase = (size_t)b * S_ * D_ + (size_t)h * HS_;
  const size_t vtbase = ((size_t)b * D_ + (size_t)h * HS_) * (size_t)S_;

  const int srow = tid >> 3;
  const int scg = (tid & 7) ^ (srow & 7);
  const int cs0 = (quad ^ (col & 7)) * 8;
  const int cs1 = ((quad + 4) ^ (col & 7)) * 8;
  short* plw = pl[wave];

  bf16x8 ones;
  for (int i = 0; i < 8; i++) ones[i] = (short)0x3F80;

  int nb = 0;

  for (int half = 0; half < 2; half++) {
    const int s = half ? (int)blockIdx.y : 31 - (int)blockIdx.y;
    const int qmin = s * 64 + wave * 16;
    const int L = s;

    load_lds16(&Kt[qkbase + (size_t)srow * D_ + scg * 8],        &lK[nb][tid * 8]);
    load_lds16(&Kt[qkbase + (size_t)(32 + srow) * D_ + scg * 8], &lK[nb][2048 + tid * 8]);
    load_lds16(&Vt[vtbase + (size_t)srow * S_ + scg * 8],        &lV[nb][tid * 8]);
    load_lds16(&Vt[vtbase + (size_t)(srow + 32) * S_ + scg * 8], &lV[nb][2048 + tid * 8]);
    const int cur0 = nb;
    nb ^= 1;

    bf16x8 qf[2];
    for (int x = 0; x < 2; x++)
      qf[x] = *(const bf16x8*)&Q[qkbase + (size_t)(qmin + col) * D_ + x * 32 + quad * 8];

    f32x4 oacc[4], lacc;
    for (int dt = 0; dt < 4; dt++) oacc[dt] = (f32x4){0.f, 0.f, 0.f, 0.f};
    lacc = (f32x4){0.f, 0.f, 0.f, 0.f};

    for (int nt = 0; nt <= L; nt++) {
      const int n0 = nt * 64;
      const int cur = cur0 ^ (nt & 1);
      __syncthreads();
      if (nt < L) {
        const int nn = n0 + 64;
        load_lds16(&Kt[qkbase + (size_t)(nn + srow) * D_ + scg * 8],      &lK[nb][tid * 8]);
        load_lds16(&Kt[qkbase + (size_t)(nn + 32 + srow) * D_ + scg * 8], &lK[nb][2048 + tid * 8]);
        load_lds16(&Vt[vtbase + (size_t)srow * S_ + nn + scg * 8],        &lV[nb][tid * 8]);
        load_lds16(&Vt[vtbase + (size_t)(srow + 32) * S_ + nn + scg * 8], &lV[nb][2048 + tid * 8]);
        nb ^= 1;
      }

      const short* lKc = lK[cur];
      const short* lVc = lV[cur];
      const bool needM = (nt == L);

      bf16x8 kf[4][2];
      for (int t = 0; t < 4; t++) {
        const int rb = (t * 16 + col) * 64;
        kf[t][0] = *(const bf16x8*)&lKc[rb + cs0];
        kf[t][1] = *(const bf16x8*)&lKc[rb + cs1];
      }

      const int qg = qmin + col;
      for (int t = 0; t < 4; t++) {
        f32x4 z = (f32x4){0.f, 0.f, 0.f, 0.f};
        __builtin_amdgcn_s_setprio(1);
        z = __builtin_amdgcn_mfma_f32_16x16x32_bf16(kf[t][0], qf[0], z, 0, 0, 0);
        z = __builtin_amdgcn_mfma_f32_16x16x32_bf16(kf[t][1], qf[1], z, 0, 0, 0);
        __builtin_amdgcn_s_setprio(0);
        float p0 = exp2f(z[0]);
        float p1 = exp2f(z[1]);
        float p2 = exp2f(z[2]);
        float p3 = exp2f(z[3]);
        if (needM) {
          const int kv = n0 + t * 16 + quad * 4;
          if (kv + 0 > qg) p0 = 0.f;
          if (kv + 1 > qg) p1 = 0.f;
          if (kv + 2 > qg) p2 = 0.f;
          if (kv + 3 > qg) p3 = 0.f;
        }
        unsigned d0 = __builtin_amdgcn_perm(fbits(p1), fbits(p0), 0x07060302u);
        unsigned d1 = __builtin_amdgcn_perm(fbits(p3), fbits(p2), 0x07060302u);
        const int cc = (2 * t + (quad >> 1)) ^ (col & 7);
        uint2 w; w.x = d0; w.y = d1;
        *(uint2*)&plw[col * 64 + cc * 8 + (quad & 1) * 4] = w;
      }

      for (int h2 = 0; h2 < 2; h2++) {
        const int cgo = ((h2 * 4 + quad) ^ (col & 7)) * 8;
        const bf16x8 pf = *(const bf16x8*)&plw[col * 64 + cgo];
        bf16x8 vf[4];
        for (int dt = 0; dt < 4; dt++)
          vf[dt] = *(const bf16x8*)&lVc[(dt * 16 + col) * 64 + cgo];
        __builtin_amdgcn_s_setprio(1);
        lacc = __builtin_amdgcn_mfma_f32_16x16x32_bf16(pf, ones, lacc, 0, 0, 0);
        for (int dt = 0; dt < 4; dt++)
          oacc[dt] = __builtin_amdgcn_mfma_f32_16x16x32_bf16(pf, vf[dt], oacc[dt], 0, 0, 0);
        __builtin_amdgcn_s_setprio(0);
      }
    }

    for (int r = 0; r < 4; r++) {
      const float inv = 1.f / lacc[r];
      const size_t row = qkbase + (size_t)(qmin + quad * 4 + r) * D_;
      for (int dt = 0; dt < 4; dt++)
        O[row + dt * 16 + col] = f2bf(oacc[dt][r] * inv);
    }
  }
}

// ---- legacy fallback kernels (small-ws paths) ----
__global__ __launch_bounds__(256) void gemm_ff(const float* __restrict__ A,
                                               const float* __restrict__ Bt,
                                               short* __restrict__ C,
                                               int M, int N, int K) {
  __shared__ __align__(16) short lA[128 * 32];
  __shared__ __align__(16) short lB[128 * 32];
  const int tid = threadIdx.x;
  const int wave = tid >> 6, lane = tid & 63;
  const int quad = lane >> 4, col = lane & 15;
  const int m0 = blockIdx.y * 128, n0 = blockIdx.x * 128;
  const int wm = (wave >> 1) * 64, wn = (wave & 1) * 64;
  const int srow2 = tid >> 1;
  const int sc = (tid & 1) * 16;

  f32x4 acc[4][4];
  for (int i = 0; i < 4; i++)
    for (int j = 0; j < 4; j++) acc[i][j] = (f32x4){0.f, 0.f, 0.f, 0.f};

  for (int k0 = 0; k0 < K; k0 += 32) {
    __syncthreads();
    {
      const float4* ga = (const float4*)&A[(size_t)(m0 + srow2) * K + k0 + sc];
      const float4 v0 = ga[0], v1 = ga[1], v2 = ga[2], v3 = ga[3];
      bf16x8 p0, p1;
      p0[0] = f2bf(v0.x); p0[1] = f2bf(v0.y); p0[2] = f2bf(v0.z); p0[3] = f2bf(v0.w);
      p0[4] = f2bf(v1.x); p0[5] = f2bf(v1.y); p0[6] = f2bf(v1.z); p0[7] = f2bf(v1.w);
      p1[0] = f2bf(v2.x); p1[1] = f2bf(v2.y); p1[2] = f2bf(v2.z); p1[3] = f2bf(v2.w);
      p1[4] = f2bf(v3.x); p1[5] = f2bf(v3.y); p1[6] = f2bf(v3.z); p1[7] = f2bf(v3.w);
      *(bf16x8*)&lA[srow2 * 32 + sc]     = p0;
      *(bf16x8*)&lA[srow2 * 32 + sc + 8] = p1;
    }
    {
      const float4* gb = (const float4*)&Bt[(size_t)(n0 + srow2) * K + k0 + sc];
      const float4 v0 = gb[0], v1 = gb[1], v2 = gb[2], v3 = gb[3];
      bf16x8 p0, p1;
      p0[0] = f2bf(v0.x); p0[1] = f2bf(v0.y); p0[2] = f2bf(v0.z); p0[3] = f2bf(v0.w);
      p0[4] = f2bf(v1.x); p0[5] = f2bf(v1.y); p0[6] = f2bf(v1.z); p0[7] = f2bf(v1.w);
      p1[0] = f2bf(v2.x); p1[1] = f2bf(v2.y); p1[2] = f2bf(v2.z); p1[3] = f2bf(v2.w);
      p1[4] = f2bf(v3.x); p1[5] = f2bf(v3.y); p1[6] = f2bf(v3.z); p1[7] = f2bf(v3.w);
      *(bf16x8*)&lB[srow2 * 32 + sc]     = p0;
      *(bf16x8*)&lB[srow2 * 32 + sc + 8] = p1;
    }
    __syncthreads();
    {
      bf16x8 af[4], bfr[4];
      for (int i = 0; i < 4; i++) af[i]  = *(const bf16x8*)&lA[(wm + i * 16 + col) * 32 + quad * 8];
      for (int j = 0; j < 4; j++) bfr[j] = *(const bf16x8*)&lB[(wn + j * 16 + col) * 32 + quad * 8];
      for (int i = 0; i < 4; i++)
        for (int j = 0; j < 4; j++)
          acc[i][j] = __builtin_amdgcn_mfma_f32_16x16x32_bf16(af[i], bfr[j], acc[i][j], 0, 0, 0);
    }
  }

  for (int j = 0; j < 4; j++) {
    const int gn = n0 + wn + j * 16 + col;
    for (int i = 0; i < 4; i++) {
      const int gm = m0 + wm + i * 16 + quad * 4;
      for (int r = 0; r < 4; r++)
        C[(size_t)(gm + r) * N + gn] = f2bf(acc[i][j][r]);
    }
  }
}

__global__ __launch_bounds__(256) void gemm_out_bf(const short* __restrict__ A,
                                                   const float* __restrict__ Bt,
                                                   float* __restrict__ C,
                                                   const float* __restrict__ bias,
                                                   int M, int N, int K) {
  __shared__ __align__(16) short lA[128 * 32];
  __shared__ __align__(16) short lB[128 * 32];
  const int tid = threadIdx.x;
  const int wave = tid >> 6, lane = tid & 63;
  const int quad = lane >> 4, col = lane & 15;
  const int m0 = blockIdx.y * 128, n0 = blockIdx.x * 128;
  const int wm = (wave >> 1) * 64, wn = (wave & 1) * 64;
  const int srow = wave * 32 + (lane >> 2);
  const int scol = (lane & 3) * 8;
  const int srow2 = tid >> 1;
  const int sc = (tid & 1) * 16;

  f32x4 acc[4][4];
  for (int i = 0; i < 4; i++)
    for (int j = 0; j < 4; j++) acc[i][j] = (f32x4){0.f, 0.f, 0.f, 0.f};

  for (int k0 = 0; k0 < K; k0 += 32) {
    __syncthreads();
    load_lds16(&A[(size_t)(m0 + srow) * K + k0 + scol],      &lA[srow * 32 + scol]);
    load_lds16(&A[(size_t)(m0 + srow + 16) * K + k0 + scol], &lA[(srow + 16) * 32 + scol]);
    {
      const float4* gb = (const float4*)&Bt[(size_t)(n0 + srow2) * K + k0 + sc];
      const float4 v0 = gb[0], v1 = gb[1], v2 = gb[2], v3 = gb[3];
      bf16x8 p0, p1;
      p0[0] = f2bf(v0.x); p0[1] = f2bf(v0.y); p0[2] = f2bf(v0.z); p0[3] = f2bf(v0.w);
      p0[4] = f2bf(v1.x); p0[5] = f2bf(v1.y); p0[6] = f2bf(v1.z); p0[7] = f2bf(v1.w);
      p1[0] = f2bf(v2.x); p1[1] = f2bf(v2.y); p1[2] = f2bf(v2.z); p1[3] = f2bf(v2.w);
      p1[4] = f2bf(v3.x); p1[5] = f2bf(v3.y); p1[6] = f2bf(v3.z); p1[7] = f2bf(v3.w);
      *(bf16x8*)&lB[srow2 * 32 + sc]     = p0;
      *(bf16x8*)&lB[srow2 * 32 + sc + 8] = p1;
    }
    __syncthreads();
    {
      bf16x8 af[4], bfr[4];
      for (int i = 0; i < 4; i++) af[i]  = *(const bf16x8*)&lA[(wm + i * 16 + col) * 32 + quad * 8];
      for (int j = 0; j < 4; j++) bfr[j] = *(const bf16x8*)&lB[(wn + j * 16 + col) * 32 + quad * 8];
      for (int i = 0; i < 4; i++)
        for (int j = 0; j < 4; j++)
          acc[i][j] = __builtin_amdgcn_mfma_f32_16x16x32_bf16(af[i], bfr[j], acc[i][j], 0, 0, 0);
    }
  }

  for (int j = 0; j < 4; j++) {
    const int gn = n0 + wn + j * 16 + col;
    const float bv = bias ? bias[gn] : 0.f;
    for (int i = 0; i < 4; i++) {
      const int gm = m0 + wm + i * 16 + quad * 4;
      for (int r = 0; r < 4; r++)
        C[(size_t)(gm + r) * N + gn] = acc[i][j][r] + bv;
    }
  }
}

__global__ __launch_bounds__(64) void flash_attn(const short* __restrict__ Q,
                                                 const short* __restrict__ K,
                                                 const short* __restrict__ V,
                                                 short* __restrict__ O) {
  __shared__ __align__(16) short pl[16 * 40];
  const int lane = threadIdx.x;
  const int quad = lane >> 4, col = lane & 15;
  const int blk = blockIdx.x;
  const int qt = blk & 127;
  const int bh = blk >> 7;
  const int b = bh >> 4, h = bh & 15;
  const int q0 = qt * 16;
  const size_t base = (size_t)b * S_ * D_ + (size_t)h * HS_;

  const bf16x8 qf0 = *(const bf16x8*)&Q[base + (size_t)(q0 + col) * D_ + quad * 8];
  const bf16x8 qf1 = *(const bf16x8*)&Q[base + (size_t)(q0 + col) * D_ + 32 + quad * 8];

  float mr[4], lr[4];
  f32x4 oacc[4];
  for (int r = 0; r < 4; r++) { mr[r] = -1e30f; lr[r] = 0.f; }
  for (int dt = 0; dt < 4; dt++) oacc[dt] = (f32x4){0.f, 0.f, 0.f, 0.f};

  const int ntiles = (q0 + 15) / 32 + 1;
  for (int nt = 0; nt < ntiles; nt++) {
    const int n0 = nt * 32;
    f32x4 s[2];
    s[0] = (f32x4){0.f, 0.f, 0.f, 0.f};
    s[1] = (f32x4){0.f, 0.f, 0.f, 0.f};
    for (int t = 0; t < 2; t++) {
      const short* kp = &K[base + (size_t)(n0 + t * 16 + col) * D_ + quad * 8];
      const bf16x8 kf0 = *(const bf16x8*)kp;
      const bf16x8 kf1 = *(const bf16x8*)(kp + 32);
      s[t] = __builtin_amdgcn_mfma_f32_16x16x32_bf16(qf0, kf0, s[t], 0, 0, 0);
      s[t] = __builtin_amdgcn_mfma_f32_16x16x32_bf16(qf1, kf1, s[t], 0, 0, 0);
    }
    for (int r = 0; r < 4; r++) {
      const int mg = q0 + quad * 4 + r;
      float s0 = s[0][r] * 0.125f; if (n0 + col > mg)      s0 = -1e30f;
      float s1 = s[1][r] * 0.125f; if (n0 + 16 + col > mg) s1 = -1e30f;
      float tm = fmaxf(s0, s1);
      for (int off = 1; off < 16; off <<= 1) tm = fmaxf(tm, __shfl_xor(tm, off));
      const float mnew = fmaxf(mr[r], tm);
      const float alpha = __expf(mr[r] - mnew);
      mr[r] = mnew;
      const float p0 = __expf(s0 - mnew);
      const float p1 = __expf(s1 - mnew);
      float ps = p0 + p1;
      for (int off = 1; off < 16; off <<= 1) ps += __shfl_xor(ps, off);
      lr[r] = lr[r] * alpha + ps;
      for (int dt = 0; dt < 4; dt++) oacc[dt][r] *= alpha;
      pl[(quad * 4 + r) * 40 + col]      = f2bf(p0);
      pl[(quad * 4 + r) * 40 + 16 + col] = f2bf(p1);
    }
    const bf16x8 pf = *(const bf16x8*)&pl[col * 40 + quad * 8];
    for (int dt = 0; dt < 4; dt++) {
      bf16x8 vf;
      const short* vp = &V[base + (size_t)(n0 + quad * 8) * D_ + dt * 16 + col];
      for (int j = 0; j < 8; j++) vf[j] = vp[(size_t)j * D_];
      oacc[dt] = __builtin_amdgcn_mfma_f32_16x16x32_bf16(pf, vf, oacc[dt], 0, 0, 0);
    }
  }

  for (int r = 0; r < 4; r++) {
    const float inv = 1.f / lr[r];
    const size_t row = base + (size_t)(q0 + quad * 4 + r) * D_;
    for (int dt = 0; dt < 4; dt++)
      O[row + dt * 16 + col] = f2bf(oacc[dt][r] * inv);
  }
}

extern "C" void kernel_launch(void* const* d_in, const int* in_sizes, int n_in,
                              void* d_out, int out_size, void* d_ws, size_t ws_size,
                              hipStream_t stream) {
  const float* x  = (const float*)d_in[0];
  const float* Wk = (const float*)d_in[1];
  const float* Wq = (const float*)d_in[2];
  const float* Wv = (const float*)d_in[3];
  const float* Wo = (const float*)d_in[4];
  const float* bo = (const float*)d_in[5];
  float* out = (float*)d_out;

  char* ws = (char*)d_ws;
  const size_t MiB = 1u << 20;
  const int M = B_ * S_, N = D_, K = D_;
  const int nx = M * D_, nw = D_ * D_;

  if (ws_size >= 88 * MiB) {
    short* xb    = (short*)(ws);
    short* wkb   = (short*)(ws + 16 * MiB);
    short* wqb   = (short*)(ws + 18 * MiB);
    short* wvb   = (short*)(ws + 20 * MiB);
    short* wob   = (short*)(ws + 22 * MiB);
    short* q_ws  = (short*)(ws + 24 * MiB);
    short* k_ws  = (short*)(ws + 40 * MiB);
    short* vt_ws = (short*)(ws + 56 * MiB);
    short* a_ws  = (short*)(ws + 72 * MiB);

    hipLaunchKernelGGL(cvt_f32_bf16, dim3(nx / 1024), dim3(256), 0, stream, x, xb, nx);
    hipLaunchKernelGGL(cvt4_f32_bf16, dim3(nw / 1024, 4), dim3(256), 0, stream,
                       Wq, Wk, Wv, Wo, wqb, wkb, wvb, wob, nw);
    hipLaunchKernelGGL(gemm_qkv8, dim3(M / 256, 12), dim3(512), 0, stream,
                       xb, wqb, wkb, wvb, q_ws, k_ws, vt_ws);
    hipLaunchKernelGGL(flash_attn6, dim3(B_ * H_, 16), dim3(256), 0, stream,
                       q_ws, k_ws, vt_ws, a_ws);
    hipLaunchKernelGGL((gemm_bb<true>), dim3(M / 128, N / 128), dim3(256), 0, stream,
                       a_ws, wob, (void*)out, bo, M, N, K);
  } else if (ws_size >= 64 * MiB) {
    short* q_ws = (short*)(ws);
    short* k_ws = (short*)(ws + 16 * MiB);
    short* v_ws = (short*)(ws + 32 * MiB);
    short* a_ws = (short*)(ws + 48 * MiB);
    dim3 gg(N / 128, M / 128), gb(256);
    hipLaunchKernelGGL(gemm_ff, gg, gb, 0, stream, x, Wq, q_ws, M, N, K);
    hipLaunchKernelGGL(gemm_ff, gg, gb, 0, stream, x, Wk, k_ws, M, N, K);
    hipLaunchKernelGGL(gemm_ff, gg, gb, 0, stream, x, Wv, v_ws, M, N, K);
    hipLaunchKernelGGL(flash_attn, dim3(B_ * H_ * (S_ / 16)), dim3(64), 0, stream, q_ws, k_ws, v_ws, a_ws);
    hipLaunchKernelGGL(gemm_out_bf, gg, gb, 0, stream, a_ws, Wo, out, bo, M, N, K);
  } else {
    short* q_ws = (short*)(ws);
    short* k_ws = (short*)(ws + 4 * MiB);
    short* v_ws = (short*)(ws + 8 * MiB);
    short* a_ws = (short*)(ws + 12 * MiB);
    const int Mb = S_;
    dim3 gg(N / 128, Mb / 128), gb(256);
    for (int b = 0; b < B_; b++) {
      const float* xb = x + (size_t)b * S_ * D_;
      float* ob = out + (size_t)b * S_ * D_;
      hipLaunchKernelGGL(gemm_ff, gg, gb, 0, stream, xb, Wq, q_ws, Mb, N, K);
      hipLaunchKernelGGL(gemm_ff, gg, gb, 0, stream, xb, Wk, k_ws, Mb, N, K);
      hipLaunchKernelGGL(gemm_ff, gg, gb, 0, stream, xb, Wv, v_ws, Mb, N, K);
      hipLaunchKernelGGL(flash_attn, dim3(H_ * (S_ / 16)), dim3(64), 0, stream, q_ws, k_ws, v_ws, a_ws);
      hipLaunchKernelGGL(gemm_out_bf, gg, gb, 0, stream, a_ws, Wo, ob, bo, Mb, N, K);
    }
  }
}

// Round 9
// 250.489 us; speedup vs baseline: 1.0673x; 1.0255x over previous
//
#include <hip/hip_runtime.h>

#define B_ 4
#define S_ 2048
#define D_ 1024
#define H_ 16
#define HS_ 64

typedef float f32x4 __attribute__((ext_vector_type(4)));
typedef short bf16x8 __attribute__((ext_vector_type(8)));

__device__ inline short f2bf(float f) {
  union { float f; unsigned u; } v; v.f = f;
  unsigned r = v.u + 0x7fffu + ((v.u >> 16) & 1u);
  return (short)(r >> 16);
}
__device__ inline unsigned fbits(float f) {
  union { float f; unsigned u; } v; v.f = f; return v.u;
}

__device__ inline void load_lds16(const short* g, short* l) {
  __builtin_amdgcn_global_load_lds((const __attribute__((address_space(1))) void*)g,
                                   (__attribute__((address_space(3))) void*)l, 16, 0, 0);
}

// fp32 -> bf16, 4 elems/thread.
__global__ __launch_bounds__(256) void cvt_f32_bf16(const float* __restrict__ in,
                                                    short* __restrict__ out, int n) {
  const int i = (blockIdx.x * 256 + threadIdx.x) * 4;
  if (i < n) {
    const float4 v = *(const float4*)(in + i);
    short4 o;
    o.x = f2bf(v.x); o.y = f2bf(v.y); o.z = f2bf(v.z); o.w = f2bf(v.w);
    *(short4*)(out + i) = o;
  }
}

// 4 weight matrices in one dispatch. grid (n/1024, 4).
__global__ __launch_bounds__(256) void cvt4_f32_bf16(const float* __restrict__ w0, const float* __restrict__ w1,
                                                     const float* __restrict__ w2, const float* __restrict__ w3,
                                                     short* __restrict__ o0, short* __restrict__ o1,
                                                     short* __restrict__ o2, short* __restrict__ o3, int n) {
  const float* in; short* out;
  switch (blockIdx.y) {
    case 0: in = w0; out = o0; break;
    case 1: in = w1; out = o1; break;
    case 2: in = w2; out = o2; break;
    default: in = w3; out = o3; break;
  }
  const int i = (blockIdx.x * 256 + threadIdx.x) * 4;
  if (i < n) {
    const float4 v = *(const float4*)(in + i);
    short4 o;
    o.x = f2bf(v.x); o.y = f2bf(v.y); o.z = f2bf(v.z); o.w = f2bf(v.w);
    *(short4*)(out + i) = o;
  }
}

// ---- BK=64 pipelined GEMM core (128^2, 2-phase) -----------------------
__device__ inline void stage_tile64(const short* __restrict__ g, int ld, int k0,
                                    short* l, int tid) {
  const int srow = tid >> 3;
  const int scol = (tid & 7) * 8;
  const int scg  = ((tid & 7) ^ ((tid >> 3) & 7)) * 8;
  for (int j = 0; j < 4; j++)
    load_lds16(&g[(size_t)(srow + j * 32) * ld + k0 + scg], &l[(srow + j * 32) * 64 + scol]);
}

__device__ inline void mfma_core64(const short* lA, const short* lB, int wm, int wn,
                                   int col, int quad, f32x4 acc[4][4]) {
  for (int ks = 0; ks < 2; ks++) {
    const int cs = ((ks * 4 + quad) ^ (col & 7)) * 8;
    bf16x8 af[4], bfr[4];
    for (int i = 0; i < 4; i++) af[i]  = *(const bf16x8*)&lA[(wm + i * 16 + col) * 64 + cs];
    for (int j = 0; j < 4; j++) bfr[j] = *(const bf16x8*)&lB[(wn + j * 16 + col) * 64 + cs];
    for (int i = 0; i < 4; i++)
      for (int j = 0; j < 4; j++)
        acc[i][j] = __builtin_amdgcn_mfma_f32_16x16x32_bf16(af[i], bfr[j], acc[i][j], 0, 0, 0);
  }
}

// Generic bf16 GEMM (r6 structure kept): BK=64, dbuf, 2-phase. grid (M/128, N/128).
template <bool CF32>
__global__ __launch_bounds__(256) void gemm_bb(const short* __restrict__ A,
                                               const short* __restrict__ Bt,
                                               void* __restrict__ Cv,
                                               const float* __restrict__ bias,
                                               int M, int N, int K) {
  __shared__ __align__(16) short lA[2][128 * 64];
  __shared__ __align__(16) short lB[2][128 * 64];
  const int tid = threadIdx.x;
  const int wave = tid >> 6, lane = tid & 63;
  const int quad = lane >> 4, col = lane & 15;
  const int m0 = blockIdx.x * 128, n0 = blockIdx.y * 128;
  const int wm = (wave >> 1) * 64, wn = (wave & 1) * 64;

  f32x4 acc[4][4];
  for (int i = 0; i < 4; i++)
    for (int j = 0; j < 4; j++) acc[i][j] = (f32x4){0.f, 0.f, 0.f, 0.f};

  const int NT = K >> 6;
  stage_tile64(&A[(size_t)m0 * K], K, 0, lA[0], tid);
  stage_tile64(&Bt[(size_t)n0 * K], K, 0, lB[0], tid);
  __syncthreads();
  for (int kt = 0; kt < NT; kt++) {
    const int cur = kt & 1;
    if (kt + 1 < NT) {
      stage_tile64(&A[(size_t)m0 * K], K, (kt + 1) * 64, lA[cur ^ 1], tid);
      stage_tile64(&Bt[(size_t)n0 * K], K, (kt + 1) * 64, lB[cur ^ 1], tid);
    }
    mfma_core64(lA[cur], lB[cur], wm, wn, col, quad, acc);
    __syncthreads();
  }

  for (int j = 0; j < 4; j++) {
    const int gn = n0 + wn + j * 16 + col;
    const float bv = bias ? bias[gn] : 0.f;
    for (int i = 0; i < 4; i++) {
      const int gm = m0 + wm + i * 16 + quad * 4;
      for (int r = 0; r < 4; r++) {
        if (CF32) ((float*)Cv)[(size_t)(gm + r) * N + gn] = acc[i][j][r] + bv;
        else      ((short*)Cv)[(size_t)(gm + r) * N + gn] = f2bf(acc[i][j][r] + bv);
      }
    }
  }
}

// ---- Fused Q/K/V projection v3: BM=128 x BN=256, triple-buffered, counted vmcnt.
// r8 post-mortem: 256^2 at grid 384 = 1.5 rounds -> 25% tail (Occ 14.9 vs 18.75
// integrated ceiling). Here grid = (8192/128) x 12 = 768 = EXACTLY 3 rounds of
// 256 resident blocks -> zero tail. 8 waves (2M x 4N), wave tile 64x64.
// LDS 3 x 48KB = 144KB triple buffer: tile t+2 stages into buf[(t+2)%3] while
// t is read -> NO in-place constraints (race-free via the per-tile barrier),
// and the t+1 gate sees loads issued a full ~2 tiles earlier (covers HBM lat;
// r8's in-place ledger gave only ~1 tile).
// 2 phases/tile x 16 MFMA keeps r8's verified barrier:MFMA ratio (4/32 = 8/64).
// Ledger: 6 loads/tile/thread (A:2 regions of 64 rows, B:4). ph0 stages
// B0,B1,B2(t+2); ph1 stages B3,A0,A1(t+2); gate at ph1 end: vmcnt(6) -> all
// but t+2's 6 retired => t+1 landed. NEVER vmcnt(0) in steady state (T4).
// Swizzle: same chunk-XOR involution (slot c holds global chunk c^(row&7));
// verified conflict-free r6/r8 (6.3M -> 0).
__global__ __launch_bounds__(512, 2) void gemm_qkv8(const short* __restrict__ A,
                                                    const short* Wq, const short* Wk, const short* Wv,
                                                    short* Cq, short* Ck, short* Cvt) {
  __shared__ __align__(16) short lds[3][24576];  // [buf][A 128x64 | B 256x64]
  const int tid = threadIdx.x;
  const int wave = tid >> 6, lane = tid & 63;
  const int quad = lane >> 4, col = lane & 15;
  const int nsel = blockIdx.y >> 2;
  const int n0 = (blockIdx.y & 3) * 256;
  const short* Bt = nsel == 0 ? Wq : (nsel == 1 ? Wk : Wv);
  const int m0 = blockIdx.x * 128;
  const int wm = (wave >> 2) * 64, wn = (wave & 3) * 64;
  const int K = D_;
  const int NT = 16;  // K/64

  const int srow = tid >> 3;   // 0..63
  const int sc8 = tid & 7;
  const short* gA = &A[(size_t)m0 * K];
  const short* gB = &Bt[(size_t)n0 * K];

  auto stageA = [&](int t, int p) {  // p = 0..1 (64 rows each)
    const int row = p * 64 + srow;
    load_lds16(&gA[(size_t)row * K + t * 64 + ((sc8 ^ (row & 7)) * 8)],
               &lds[t % 3][row * 64 + sc8 * 8]);
  };
  auto stageB = [&](int t, int p) {  // p = 0..3 (64 rows each)
    const int row = p * 64 + srow;
    load_lds16(&gB[(size_t)row * K + t * 64 + ((sc8 ^ (row & 7)) * 8)],
               &lds[t % 3][8192 + row * 64 + sc8 * 8]);
  };

  f32x4 acc[4][4];
#pragma unroll
  for (int i = 0; i < 4; i++)
#pragma unroll
    for (int j = 0; j < 4; j++) acc[i][j] = (f32x4){0.f, 0.f, 0.f, 0.f};

  // Prologue: tile0 (6 loads, oldest) then tile1 (6).
  stageA(0, 0); stageA(0, 1);
  for (int p = 0; p < 4; p++) stageB(0, p);
  stageA(1, 0); stageA(1, 1);
  for (int p = 0; p < 4; p++) stageB(1, p);
  asm volatile("s_waitcnt vmcnt(6)" ::: "memory");  // tile0's 6 landed
  __builtin_amdgcn_sched_barrier(0);
  __builtin_amdgcn_s_barrier();

  for (int t = 0; t < NT; t++) {
    const short* la = lds[t % 3];
    const short* lb = la + 8192;

    bf16x8 bfr[4][2];
    // ---- phase 0: i-strips 0,1 ----
    {
      bf16x8 af[2][2];
#pragma unroll
      for (int j = 0; j < 4; j++)
#pragma unroll
        for (int kk = 0; kk < 2; kk++)
          bfr[j][kk] = *(const bf16x8*)&lb[(wn + j * 16 + col) * 64 +
                                           (((kk * 4 + quad) ^ (col & 7)) * 8)];
#pragma unroll
      for (int f = 0; f < 2; f++)
#pragma unroll
        for (int kk = 0; kk < 2; kk++)
          af[f][kk] = *(const bf16x8*)&la[(wm + f * 16 + col) * 64 +
                                          (((kk * 4 + quad) ^ (col & 7)) * 8)];
      if (t + 2 < NT) { stageB(t + 2, 0); stageB(t + 2, 1); stageB(t + 2, 2); }
      __builtin_amdgcn_sched_barrier(0);
      __builtin_amdgcn_s_barrier();
      asm volatile("s_waitcnt lgkmcnt(0)" ::: "memory");
      __builtin_amdgcn_sched_barrier(0);
      __builtin_amdgcn_s_setprio(1);
#pragma unroll
      for (int f = 0; f < 2; f++)
#pragma unroll
        for (int j = 0; j < 4; j++)
#pragma unroll
          for (int kk = 0; kk < 2; kk++)
            acc[f][j] = __builtin_amdgcn_mfma_f32_16x16x32_bf16(
                af[f][kk], bfr[j][kk], acc[f][j], 0, 0, 0);
      __builtin_amdgcn_s_setprio(0);
      __builtin_amdgcn_sched_barrier(0);
      __builtin_amdgcn_s_barrier();
    }
    // ---- phase 1: i-strips 2,3 ----
    {
      bf16x8 af[2][2];
#pragma unroll
      for (int f = 0; f < 2; f++)
#pragma unroll
        for (int kk = 0; kk < 2; kk++)
          af[f][kk] = *(const bf16x8*)&la[(wm + (2 + f) * 16 + col) * 64 +
                                          (((kk * 4 + quad) ^ (col & 7)) * 8)];
      if (t + 2 < NT) { stageB(t + 2, 3); stageA(t + 2, 0); stageA(t + 2, 1); }
      __builtin_amdgcn_sched_barrier(0);
      __builtin_amdgcn_s_barrier();
      asm volatile("s_waitcnt lgkmcnt(0)" ::: "memory");
      __builtin_amdgcn_sched_barrier(0);
      __builtin_amdgcn_s_setprio(1);
#pragma unroll
      for (int f = 0; f < 2; f++)
#pragma unroll
        for (int j = 0; j < 4; j++)
#pragma unroll
          for (int kk = 0; kk < 2; kk++)
            acc[2 + f][j] = __builtin_amdgcn_mfma_f32_16x16x32_bf16(
                af[f][kk], bfr[j][kk], acc[2 + f][j], 0, 0, 0);
      __builtin_amdgcn_s_setprio(0);
      if (t + 2 < NT)      { asm volatile("s_waitcnt vmcnt(6)" ::: "memory"); }
      else if (t + 1 < NT) { asm volatile("s_waitcnt vmcnt(0)" ::: "memory"); }
      __builtin_amdgcn_sched_barrier(0);
      __builtin_amdgcn_s_barrier();
    }
  }

  if (nsel < 2) {
    short* C = nsel ? Ck : Cq;
    const float sc = nsel == 0 ? 0.18033688f : 1.0f;  // 0.125 * log2(e)
    for (int j = 0; j < 4; j++) {
      const int gn = n0 + wn + j * 16 + col;
      for (int i = 0; i < 4; i++) {
        const int gm = m0 + wm + i * 16 + quad * 4;
        for (int r = 0; r < 4; r++)
          C[(size_t)(gm + r) * D_ + gn] = f2bf(acc[i][j][r] * sc);
      }
    }
  } else {
    for (int j = 0; j < 4; j++) {
      const int gn = n0 + wn + j * 16 + col;
      for (int i = 0; i < 4; i++) {
        const int gm = m0 + wm + i * 16 + quad * 4;
        const int bb = gm >> 11, s = gm & 2047;
        short4 o;
        o.x = f2bf(acc[i][j][0]); o.y = f2bf(acc[i][j][1]);
        o.z = f2bf(acc[i][j][2]); o.w = f2bf(acc[i][j][3]);
        *(short4*)&Cvt[((size_t)bb * D_ + gn) * (size_t)S_ + s] = o;
      }
    }
  }
}

// Flash attention v9: uniform pairing at 64-row q-slab granularity.
// Verified r5: total 283->266; r8 counters: 77us, MfmaUtil 21.8, VALU 59.6.
__global__ __launch_bounds__(256) void flash_attn6(const short* __restrict__ Q,
                                                   const short* __restrict__ Kt,
                                                   const short* __restrict__ Vt,
                                                   short* __restrict__ O) {
  __shared__ __align__(16) short lK[2][64 * 64];
  __shared__ __align__(16) short lV[2][64 * 64];
  __shared__ __align__(16) short pl[4][16 * 64];
  const int tid = threadIdx.x, wave = tid >> 6, lane = tid & 63;
  const int quad = lane >> 4, col = lane & 15;
  const int bh = blockIdx.x;
  const int b = bh >> 4, h = bh & 15;
  const size_t qkbase = (size_t)b * S_ * D_ + (size_t)h * HS_;
  const size_t vtbase = ((size_t)b * D_ + (size_t)h * HS_) * (size_t)S_;

  const int srow = tid >> 3;
  const int scg = (tid & 7) ^ (srow & 7);
  const int cs0 = (quad ^ (col & 7)) * 8;
  const int cs1 = ((quad + 4) ^ (col & 7)) * 8;
  short* plw = pl[wave];

  bf16x8 ones;
  for (int i = 0; i < 8; i++) ones[i] = (short)0x3F80;

  int nb = 0;

  for (int half = 0; half < 2; half++) {
    const int s = half ? (int)blockIdx.y : 31 - (int)blockIdx.y;
    const int qmin = s * 64 + wave * 16;
    const int L = s;

    load_lds16(&Kt[qkbase + (size_t)srow * D_ + scg * 8],        &lK[nb][tid * 8]);
    load_lds16(&Kt[qkbase + (size_t)(32 + srow) * D_ + scg * 8], &lK[nb][2048 + tid * 8]);
    load_lds16(&Vt[vtbase + (size_t)srow * S_ + scg * 8],        &lV[nb][tid * 8]);
    load_lds16(&Vt[vtbase + (size_t)(srow + 32) * S_ + scg * 8], &lV[nb][2048 + tid * 8]);
    const int cur0 = nb;
    nb ^= 1;

    bf16x8 qf[2];
    for (int x = 0; x < 2; x++)
      qf[x] = *(const bf16x8*)&Q[qkbase + (size_t)(qmin + col) * D_ + x * 32 + quad * 8];

    f32x4 oacc[4], lacc;
    for (int dt = 0; dt < 4; dt++) oacc[dt] = (f32x4){0.f, 0.f, 0.f, 0.f};
    lacc = (f32x4){0.f, 0.f, 0.f, 0.f};

    for (int nt = 0; nt <= L; nt++) {
      const int n0 = nt * 64;
      const int cur = cur0 ^ (nt & 1);
      __syncthreads();
      if (nt < L) {
        const int nn = n0 + 64;
        load_lds16(&Kt[qkbase + (size_t)(nn + srow) * D_ + scg * 8],      &lK[nb][tid * 8]);
        load_lds16(&Kt[qkbase + (size_t)(nn + 32 + srow) * D_ + scg * 8], &lK[nb][2048 + tid * 8]);
        load_lds16(&Vt[vtbase + (size_t)srow * S_ + nn + scg * 8],        &lV[nb][tid * 8]);
        load_lds16(&Vt[vtbase + (size_t)(srow + 32) * S_ + nn + scg * 8], &lV[nb][2048 + tid * 8]);
        nb ^= 1;
      }

      const short* lKc = lK[cur];
      const short* lVc = lV[cur];
      const bool needM = (nt == L);

      bf16x8 kf[4][2];
      for (int t = 0; t < 4; t++) {
        const int rb = (t * 16 + col) * 64;
        kf[t][0] = *(const bf16x8*)&lKc[rb + cs0];
        kf[t][1] = *(const bf16x8*)&lKc[rb + cs1];
      }

      const int qg = qmin + col;
      for (int t = 0; t < 4; t++) {
        f32x4 z = (f32x4){0.f, 0.f, 0.f, 0.f};
        __builtin_amdgcn_s_setprio(1);
        z = __builtin_amdgcn_mfma_f32_16x16x32_bf16(kf[t][0], qf[0], z, 0, 0, 0);
        z = __builtin_amdgcn_mfma_f32_16x16x32_bf16(kf[t][1], qf[1], z, 0, 0, 0);
        __builtin_amdgcn_s_setprio(0);
        float p0 = exp2f(z[0]);
        float p1 = exp2f(z[1]);
        float p2 = exp2f(z[2]);
        float p3 = exp2f(z[3]);
        if (needM) {
          const int kv = n0 + t * 16 + quad * 4;
          if (kv + 0 > qg) p0 = 0.f;
          if (kv + 1 > qg) p1 = 0.f;
          if (kv + 2 > qg) p2 = 0.f;
          if (kv + 3 > qg) p3 = 0.f;
        }
        unsigned d0 = __builtin_amdgcn_perm(fbits(p1), fbits(p0), 0x07060302u);
        unsigned d1 = __builtin_amdgcn_perm(fbits(p3), fbits(p2), 0x07060302u);
        const int cc = (2 * t + (quad >> 1)) ^ (col & 7);
        uint2 w; w.x = d0; w.y = d1;
        *(uint2*)&plw[col * 64 + cc * 8 + (quad & 1) * 4] = w;
      }

      for (int h2 = 0; h2 < 2; h2++) {
        const int cgo = ((h2 * 4 + quad) ^ (col & 7)) * 8;
        const bf16x8 pf = *(const bf16x8*)&plw[col * 64 + cgo];
        bf16x8 vf[4];
        for (int dt = 0; dt < 4; dt++)
          vf[dt] = *(const bf16x8*)&lVc[(dt * 16 + col) * 64 + cgo];
        __builtin_amdgcn_s_setprio(1);
        lacc = __builtin_amdgcn_mfma_f32_16x16x32_bf16(pf, ones, lacc, 0, 0, 0);
        for (int dt = 0; dt < 4; dt++)
          oacc[dt] = __builtin_amdgcn_mfma_f32_16x16x32_bf16(pf, vf[dt], oacc[dt], 0, 0, 0);
        __builtin_amdgcn_s_setprio(0);
      }
    }

    for (int r = 0; r < 4; r++) {
      const float inv = 1.f / lacc[r];
      const size_t row = qkbase + (size_t)(qmin + quad * 4 + r) * D_;
      for (int dt = 0; dt < 4; dt++)
        O[row + dt * 16 + col] = f2bf(oacc[dt][r] * inv);
    }
  }
}

// ---- legacy fallback kernels (small-ws paths) ----
__global__ __launch_bounds__(256) void gemm_ff(const float* __restrict__ A,
                                               const float* __restrict__ Bt,
                                               short* __restrict__ C,
                                               int M, int N, int K) {
  __shared__ __align__(16) short lA[128 * 32];
  __shared__ __align__(16) short lB[128 * 32];
  const int tid = threadIdx.x;
  const int wave = tid >> 6, lane = tid & 63;
  const int quad = lane >> 4, col = lane & 15;
  const int m0 = blockIdx.y * 128, n0 = blockIdx.x * 128;
  const int wm = (wave >> 1) * 64, wn = (wave & 1) * 64;
  const int srow2 = tid >> 1;
  const int sc = (tid & 1) * 16;

  f32x4 acc[4][4];
  for (int i = 0; i < 4; i++)
    for (int j = 0; j < 4; j++) acc[i][j] = (f32x4){0.f, 0.f, 0.f, 0.f};

  for (int k0 = 0; k0 < K; k0 += 32) {
    __syncthreads();
    {
      const float4* ga = (const float4*)&A[(size_t)(m0 + srow2) * K + k0 + sc];
      const float4 v0 = ga[0], v1 = ga[1], v2 = ga[2], v3 = ga[3];
      bf16x8 p0, p1;
      p0[0] = f2bf(v0.x); p0[1] = f2bf(v0.y); p0[2] = f2bf(v0.z); p0[3] = f2bf(v0.w);
      p0[4] = f2bf(v1.x); p0[5] = f2bf(v1.y); p0[6] = f2bf(v1.z); p0[7] = f2bf(v1.w);
      p1[0] = f2bf(v2.x); p1[1] = f2bf(v2.y); p1[2] = f2bf(v2.z); p1[3] = f2bf(v2.w);
      p1[4] = f2bf(v3.x); p1[5] = f2bf(v3.y); p1[6] = f2bf(v3.z); p1[7] = f2bf(v3.w);
      *(bf16x8*)&lA[srow2 * 32 + sc]     = p0;
      *(bf16x8*)&lA[srow2 * 32 + sc + 8] = p1;
    }
    {
      const float4* gb = (const float4*)&Bt[(size_t)(n0 + srow2) * K + k0 + sc];
      const float4 v0 = gb[0], v1 = gb[1], v2 = gb[2], v3 = gb[3];
      bf16x8 p0, p1;
      p0[0] = f2bf(v0.x); p0[1] = f2bf(v0.y); p0[2] = f2bf(v0.z); p0[3] = f2bf(v0.w);
      p0[4] = f2bf(v1.x); p0[5] = f2bf(v1.y); p0[6] = f2bf(v1.z); p0[7] = f2bf(v1.w);
      p1[0] = f2bf(v2.x); p1[1] = f2bf(v2.y); p1[2] = f2bf(v2.z); p1[3] = f2bf(v2.w);
      p1[4] = f2bf(v3.x); p1[5] = f2bf(v3.y); p1[6] = f2bf(v3.z); p1[7] = f2bf(v3.w);
      *(bf16x8*)&lB[srow2 * 32 + sc]     = p0;
      *(bf16x8*)&lB[srow2 * 32 + sc + 8] = p1;
    }
    __syncthreads();
    {
      bf16x8 af[4], bfr[4];
      for (int i = 0; i < 4; i++) af[i]  = *(const bf16x8*)&lA[(wm + i * 16 + col) * 32 + quad * 8];
      for (int j = 0; j < 4; j++) bfr[j] = *(const bf16x8*)&lB[(wn + j * 16 + col) * 32 + quad * 8];
      for (int i = 0; i < 4; i++)
        for (int j = 0; j < 4; j++)
          acc[i][j] = __builtin_amdgcn_mfma_f32_16x16x32_bf16(af[i], bfr[j], acc[i][j], 0, 0, 0);
    }
  }

  for (int j = 0; j < 4; j++) {
    const int gn = n0 + wn + j * 16 + col;
    for (int i = 0; i < 4; i++) {
      const int gm = m0 + wm + i * 16 + quad * 4;
      for (int r = 0; r < 4; r++)
        C[(size_t)(gm + r) * N + gn] = f2bf(acc[i][j][r]);
    }
  }
}

__global__ __launch_bounds__(256) void gemm_out_bf(const short* __restrict__ A,
                                                   const float* __restrict__ Bt,
                                                   float* __restrict__ C,
                                                   const float* __restrict__ bias,
                                                   int M, int N, int K) {
  __shared__ __align__(16) short lA[128 * 32];
  __shared__ __align__(16) short lB[128 * 32];
  const int tid = threadIdx.x;
  const int wave = tid >> 6, lane = tid & 63;
  const int quad = lane >> 4, col = lane & 15;
  const int m0 = blockIdx.y * 128, n0 = blockIdx.x * 128;
  const int wm = (wave >> 1) * 64, wn = (wave & 1) * 64;
  const int srow = wave * 32 + (lane >> 2);
  const int scol = (lane & 3) * 8;
  const int srow2 = tid >> 1;
  const int sc = (tid & 1) * 16;

  f32x4 acc[4][4];
  for (int i = 0; i < 4; i++)
    for (int j = 0; j < 4; j++) acc[i][j] = (f32x4){0.f, 0.f, 0.f, 0.f};

  for (int k0 = 0; k0 < K; k0 += 32) {
    __syncthreads();
    load_lds16(&A[(size_t)(m0 + srow) * K + k0 + scol],      &lA[srow * 32 + scol]);
    load_lds16(&A[(size_t)(m0 + srow + 16) * K + k0 + scol], &lA[(srow + 16) * 32 + scol]);
    {
      const float4* gb = (const float4*)&Bt[(size_t)(n0 + srow2) * K + k0 + sc];
      const float4 v0 = gb[0], v1 = gb[1], v2 = gb[2], v3 = gb[3];
      bf16x8 p0, p1;
      p0[0] = f2bf(v0.x); p0[1] = f2bf(v0.y); p0[2] = f2bf(v0.z); p0[3] = f2bf(v0.w);
      p0[4] = f2bf(v1.x); p0[5] = f2bf(v1.y); p0[6] = f2bf(v1.z); p0[7] = f2bf(v1.w);
      p1[0] = f2bf(v2.x); p1[1] = f2bf(v2.y); p1[2] = f2bf(v2.z); p1[3] = f2bf(v2.w);
      p1[4] = f2bf(v3.x); p1[5] = f2bf(v3.y); p1[6] = f2bf(v3.z); p1[7] = f2bf(v3.w);
      *(bf16x8*)&lB[srow2 * 32 + sc]     = p0;
      *(bf16x8*)&lB[srow2 * 32 + sc + 8] = p1;
    }
    __syncthreads();
    {
      bf16x8 af[4], bfr[4];
      for (int i = 0; i < 4; i++) af[i]  = *(const bf16x8*)&lA[(wm + i * 16 + col) * 32 + quad * 8];
      for (int j = 0; j < 4; j++) bfr[j] = *(const bf16x8*)&lB[(wn + j * 16 + col) * 32 + quad * 8];
      for (int i = 0; i < 4; i++)
        for (int j = 0; j < 4; j++)
          acc[i][j] = __builtin_amdgcn_mfma_f32_16x16x32_bf16(af[i], bfr[j], acc[i][j], 0, 0, 0);
    }
  }

  for (int j = 0; j < 4; j++) {
    const int gn = n0 + wn + j * 16 + col;
    const float bv = bias ? bias[gn] : 0.f;
    for (int i = 0; i < 4; i++) {
      const int gm = m0 + wm + i * 16 + quad * 4;
      for (int r = 0; r < 4; r++)
        C[(size_t)(gm + r) * N + gn] = acc[i][j][r] + bv;
    }
  }
}

__global__ __launch_bounds__(64) void flash_attn(const short* __restrict__ Q,
                                                 const short* __restrict__ K,
                                                 const short* __restrict__ V,
                                                 short* __restrict__ O) {
  __shared__ __align__(16) short pl[16 * 40];
  const int lane = threadIdx.x;
  const int quad = lane >> 4, col = lane & 15;
  const int blk = blockIdx.x;
  const int qt = blk & 127;
  const int bh = blk >> 7;
  const int b = bh >> 4, h = bh & 15;
  const int q0 = qt * 16;
  const size_t base = (size_t)b * S_ * D_ + (size_t)h * HS_;

  const bf16x8 qf0 = *(const bf16x8*)&Q[base + (size_t)(q0 + col) * D_ + quad * 8];
  const bf16x8 qf1 = *(const bf16x8*)&Q[base + (size_t)(q0 + col) * D_ + 32 + quad * 8];

  float mr[4], lr[4];
  f32x4 oacc[4];
  for (int r = 0; r < 4; r++) { mr[r] = -1e30f; lr[r] = 0.f; }
  for (int dt = 0; dt < 4; dt++) oacc[dt] = (f32x4){0.f, 0.f, 0.f, 0.f};

  const int ntiles = (q0 + 15) / 32 + 1;
  for (int nt = 0; nt < ntiles; nt++) {
    const int n0 = nt * 32;
    f32x4 s[2];
    s[0] = (f32x4){0.f, 0.f, 0.f, 0.f};
    s[1] = (f32x4){0.f, 0.f, 0.f, 0.f};
    for (int t = 0; t < 2; t++) {
      const short* kp = &K[base + (size_t)(n0 + t * 16 + col) * D_ + quad * 8];
      const bf16x8 kf0 = *(const bf16x8*)kp;
      const bf16x8 kf1 = *(const bf16x8*)(kp + 32);
      s[t] = __builtin_amdgcn_mfma_f32_16x16x32_bf16(qf0, kf0, s[t], 0, 0, 0);
      s[t] = __builtin_amdgcn_mfma_f32_16x16x32_bf16(qf1, kf1, s[t], 0, 0, 0);
    }
    for (int r = 0; r < 4; r++) {
      const int mg = q0 + quad * 4 + r;
      float s0 = s[0][r] * 0.125f; if (n0 + col > mg)      s0 = -1e30f;
      float s1 = s[1][r] * 0.125f; if (n0 + 16 + col > mg) s1 = -1e30f;
      float tm = fmaxf(s0, s1);
      for (int off = 1; off < 16; off <<= 1) tm = fmaxf(tm, __shfl_xor(tm, off));
      const float mnew = fmaxf(mr[r], tm);
      const float alpha = __expf(mr[r] - mnew);
      mr[r] = mnew;
      const float p0 = __expf(s0 - mnew);
      const float p1 = __expf(s1 - mnew);
      float ps = p0 + p1;
      for (int off = 1; off < 16; off <<= 1) ps += __shfl_xor(ps, off);
      lr[r] = lr[r] * alpha + ps;
      for (int dt = 0; dt < 4; dt++) oacc[dt][r] *= alpha;
      pl[(quad * 4 + r) * 40 + col]      = f2bf(p0);
      pl[(quad * 4 + r) * 40 + 16 + col] = f2bf(p1);
    }
    const bf16x8 pf = *(const bf16x8*)&pl[col * 40 + quad * 8];
    for (int dt = 0; dt < 4; dt++) {
      bf16x8 vf;
      const short* vp = &V[base + (size_t)(n0 + quad * 8) * D_ + dt * 16 + col];
      for (int j = 0; j < 8; j++) vf[j] = vp[(size_t)j * D_];
      oacc[dt] = __builtin_amdgcn_mfma_f32_16x16x32_bf16(pf, vf, oacc[dt], 0, 0, 0);
    }
  }

  for (int r = 0; r < 4; r++) {
    const float inv = 1.f / lr[r];
    const size_t row = base + (size_t)(q0 + quad * 4 + r) * D_;
    for (int dt = 0; dt < 4; dt++)
      O[row + dt * 16 + col] = f2bf(oacc[dt][r] * inv);
  }
}

extern "C" void kernel_launch(void* const* d_in, const int* in_sizes, int n_in,
                              void* d_out, int out_size, void* d_ws, size_t ws_size,
                              hipStream_t stream) {
  const float* x  = (const float*)d_in[0];
  const float* Wk = (const float*)d_in[1];
  const float* Wq = (const float*)d_in[2];
  const float* Wv = (const float*)d_in[3];
  const float* Wo = (const float*)d_in[4];
  const float* bo = (const float*)d_in[5];
  float* out = (float*)d_out;

  char* ws = (char*)d_ws;
  const size_t MiB = 1u << 20;
  const int M = B_ * S_, N = D_, K = D_;
  const int nx = M * D_, nw = D_ * D_;

  if (ws_size >= 88 * MiB) {
    short* xb    = (short*)(ws);
    short* wkb   = (short*)(ws + 16 * MiB);
    short* wqb   = (short*)(ws + 18 * MiB);
    short* wvb   = (short*)(ws + 20 * MiB);
    short* wob   = (short*)(ws + 22 * MiB);
    short* q_ws  = (short*)(ws + 24 * MiB);
    short* k_ws  = (short*)(ws + 40 * MiB);
    short* vt_ws = (short*)(ws + 56 * MiB);
    short* a_ws  = (short*)(ws + 72 * MiB);

    hipLaunchKernelGGL(cvt_f32_bf16, dim3(nx / 1024), dim3(256), 0, stream, x, xb, nx);
    hipLaunchKernelGGL(cvt4_f32_bf16, dim3(nw / 1024, 4), dim3(256), 0, stream,
                       Wq, Wk, Wv, Wo, wqb, wkb, wvb, wob, nw);
    hipLaunchKernelGGL(gemm_qkv8, dim3(M / 128, 12), dim3(512), 0, stream,
                       xb, wqb, wkb, wvb, q_ws, k_ws, vt_ws);
    hipLaunchKernelGGL(flash_attn6, dim3(B_ * H_, 16), dim3(256), 0, stream,
                       q_ws, k_ws, vt_ws, a_ws);
    hipLaunchKernelGGL((gemm_bb<true>), dim3(M / 128, N / 128), dim3(256), 0, stream,
                       a_ws, wob, (void*)out, bo, M, N, K);
  } else if (ws_size >= 64 * MiB) {
    short* q_ws = (short*)(ws);
    short* k_ws = (short*)(ws + 16 * MiB);
    short* v_ws = (short*)(ws + 32 * MiB);
    short* a_ws = (short*)(ws + 48 * MiB);
    dim3 gg(N / 128, M / 128), gb(256);
    hipLaunchKernelGGL(gemm_ff, gg, gb, 0, stream, x, Wq, q_ws, M, N, K);
    hipLaunchKernelGGL(gemm_ff, gg, gb, 0, stream, x, Wk, k_ws, M, N, K);
    hipLaunchKernelGGL(gemm_ff, gg, gb, 0, stream, x, Wv, v_ws, M, N, K);
    hipLaunchKernelGGL(flash_attn, dim3(B_ * H_ * (S_ / 16)), dim3(64), 0, stream, q_ws, k_ws, v_ws, a_ws);
    hipLaunchKernelGGL(gemm_out_bf, gg, gb, 0, stream, a_ws, Wo, out, bo, M, N, K);
  } else {
    short* q_ws = (short*)(ws);
    short* k_ws = (short*)(ws + 4 * MiB);
    short* v_ws = (short*)(ws + 8 * MiB);
    short* a_ws = (short*)(ws + 12 * MiB);
    const int Mb = S_;
    dim3 gg(N / 128, Mb / 128), gb(256);
    for (int b = 0; b < B_; b++) {
      const float* xb = x + (size_t)b * S_ * D_;
      float* ob = out + (size_t)b * S_ * D_;
      hipLaunchKernelGGL(gemm_ff, gg, gb, 0, stream, xb, Wq, q_ws, Mb, N, K);
      hipLaunchKernelGGL(gemm_ff, gg, gb, 0, stream, xb, Wk, k_ws, Mb, N, K);
      hipLaunchKernelGGL(gemm_ff, gg, gb, 0, stream, xb, Wv, v_ws, Mb, N, K);
      hipLaunchKernelGGL(flash_attn, dim3(H_ * (S_ / 16)), dim3(64), 0, stream, q_ws, k_ws, v_ws, a_ws);
      hipLaunchKernelGGL(gemm_out_bf, gg, gb, 0, stream, a_ws, Wo, ob, bo, Mb, N, K);
    }
  }
}

// Round 14
// 230.622 us; speedup vs baseline: 1.1593x; 1.0861x over previous
//
#include <hip/hip_runtime.h>

#define B_ 4
#define S_ 2048
#define D_ 1024
#define H_ 16
#define HS_ 64

typedef float f32x4 __attribute__((ext_vector_type(4)));
typedef short bf16x8 __attribute__((ext_vector_type(8)));

__device__ inline short f2bf(float f) {
  union { float f; unsigned u; } v; v.f = f;
  unsigned r = v.u + 0x7fffu + ((v.u >> 16) & 1u);
  return (short)(r >> 16);
}
__device__ inline unsigned fbits(float f) {
  union { float f; unsigned u; } v; v.f = f; return v.u;
}
// Raw v_exp_f32 (2^x). NOT __exp2f (glibc macro collision, r10 compile fail).
__device__ inline float fexp2(float x) { return __builtin_amdgcn_exp2f(x); }

__device__ inline void load_lds16(const short* g, short* l) {
  __builtin_amdgcn_global_load_lds((const __attribute__((address_space(1))) void*)g,
                                   (__attribute__((address_space(3))) void*)l, 16, 0, 0);
}

// fp32 -> bf16, 4 elems/thread.
__global__ __launch_bounds__(256) void cvt_f32_bf16(const float* __restrict__ in,
                                                    short* __restrict__ out, int n) {
  const int i = (blockIdx.x * 256 + threadIdx.x) * 4;
  if (i < n) {
    const float4 v = *(const float4*)(in + i);
    short4 o;
    o.x = f2bf(v.x); o.y = f2bf(v.y); o.z = f2bf(v.z); o.w = f2bf(v.w);
    *(short4*)(out + i) = o;
  }
}

// 4 weight matrices in one dispatch. grid (n/1024, 4).
__global__ __launch_bounds__(256) void cvt4_f32_bf16(const float* __restrict__ w0, const float* __restrict__ w1,
                                                     const float* __restrict__ w2, const float* __restrict__ w3,
                                                     short* __restrict__ o0, short* __restrict__ o1,
                                                     short* __restrict__ o2, short* __restrict__ o3, int n) {
  const float* in; short* out;
  switch (blockIdx.y) {
    case 0: in = w0; out = o0; break;
    case 1: in = w1; out = o1; break;
    case 2: in = w2; out = o2; break;
    default: in = w3; out = o3; break;
  }
  const int i = (blockIdx.x * 256 + threadIdx.x) * 4;
  if (i < n) {
    const float4 v = *(const float4*)(in + i);
    short4 o;
    o.x = f2bf(v.x); o.y = f2bf(v.y); o.z = f2bf(v.z); o.w = f2bf(v.w);
    *(short4*)(out + i) = o;
  }
}

// ---- BK=64 pipelined GEMM core (128^2, 2-phase, fallback paths) -------
__device__ inline void stage_tile64(const short* __restrict__ g, int ld, int k0,
                                    short* l, int tid) {
  const int srow = tid >> 3;
  const int scol = (tid & 7) * 8;
  const int scg  = ((tid & 7) ^ ((tid >> 3) & 7)) * 8;
  for (int j = 0; j < 4; j++)
    load_lds16(&g[(size_t)(srow + j * 32) * ld + k0 + scg], &l[(srow + j * 32) * 64 + scol]);
}

__device__ inline void mfma_core64(const short* lA, const short* lB, int wm, int wn,
                                   int col, int quad, f32x4 acc[4][4]) {
  for (int ks = 0; ks < 2; ks++) {
    const int cs = ((ks * 4 + quad) ^ (col & 7)) * 8;
    bf16x8 af[4], bfr[4];
    for (int i = 0; i < 4; i++) af[i]  = *(const bf16x8*)&lA[(wm + i * 16 + col) * 64 + cs];
    for (int j = 0; j < 4; j++) bfr[j] = *(const bf16x8*)&lB[(wn + j * 16 + col) * 64 + cs];
    for (int i = 0; i < 4; i++)
      for (int j = 0; j < 4; j++)
        acc[i][j] = __builtin_amdgcn_mfma_f32_16x16x32_bf16(af[i], bfr[j], acc[i][j], 0, 0, 0);
  }
}

// Generic bf16 GEMM (fallback): BK=64, dbuf, 2-phase. grid (M/128, N/128).
template <bool CF32>
__global__ __launch_bounds__(256) void gemm_bb(const short* __restrict__ A,
                                               const short* __restrict__ Bt,
                                               void* __restrict__ Cv,
                                               const float* __restrict__ bias,
                                               int M, int N, int K) {
  __shared__ __align__(16) short lA[2][128 * 64];
  __shared__ __align__(16) short lB[2][128 * 64];
  const int tid = threadIdx.x;
  const int wave = tid >> 6, lane = tid & 63;
  const int quad = lane >> 4, col = lane & 15;
  const int m0 = blockIdx.x * 128, n0 = blockIdx.y * 128;
  const int wm = (wave >> 1) * 64, wn = (wave & 1) * 64;

  f32x4 acc[4][4];
  for (int i = 0; i < 4; i++)
    for (int j = 0; j < 4; j++) acc[i][j] = (f32x4){0.f, 0.f, 0.f, 0.f};

  const int NT = K >> 6;
  stage_tile64(&A[(size_t)m0 * K], K, 0, lA[0], tid);
  stage_tile64(&Bt[(size_t)n0 * K], K, 0, lB[0], tid);
  __syncthreads();
  for (int kt = 0; kt < NT; kt++) {
    const int cur = kt & 1;
    if (kt + 1 < NT) {
      stage_tile64(&A[(size_t)m0 * K], K, (kt + 1) * 64, lA[cur ^ 1], tid);
      stage_tile64(&Bt[(size_t)n0 * K], K, (kt + 1) * 64, lB[cur ^ 1], tid);
    }
    mfma_core64(lA[cur], lB[cur], wm, wn, col, quad, acc);
    __syncthreads();
  }

  for (int j = 0; j < 4; j++) {
    const int gn = n0 + wn + j * 16 + col;
    const float bv = bias ? bias[gn] : 0.f;
    for (int i = 0; i < 4; i++) {
      const int gm = m0 + wm + i * 16 + quad * 4;
      for (int r = 0; r < 4; r++) {
        if (CF32) ((float*)Cv)[(size_t)(gm + r) * N + gn] = acc[i][j][r] + bv;
        else      ((short*)Cv)[(size_t)(gm + r) * N + gn] = f2bf(acc[i][j][r] + bv);
      }
    }
  }
}

// ---- v3 pipelined core: BM=128 x BN=256, triple-buffered, counted vmcnt.
// Verified r9 (gemm_qkv8: refcheck pass, conflicts 0). Ledger: 6 loads/tile/
// thread; ph0 stages B0,B1,B2(t+2); ph1 stages B3,A0,A1(t+2); gate vmcnt(6)
// at ph1 end -> tile t+1 landed; never vmcnt(0) in steady state (T4).
// NOTE: grid MUST be (M/128, 12) -- BM=128 (r12 transcription bug: M/256).
__global__ __launch_bounds__(512, 2) void gemm_qkv8(const short* __restrict__ A,
                                                    const short* Wq, const short* Wk, const short* Wv,
                                                    short* Cq, short* Ck, short* Cvt) {
  __shared__ __align__(16) short lds[3][24576];  // [buf][A 128x64 | B 256x64]
  const int tid = threadIdx.x;
  const int wave = tid >> 6, lane = tid & 63;
  const int quad = lane >> 4, col = lane & 15;
  const int nsel = blockIdx.y >> 2;
  const int n0 = (blockIdx.y & 3) * 256;
  const short* Bt = nsel == 0 ? Wq : (nsel == 1 ? Wk : Wv);
  const int m0 = blockIdx.x * 128;
  const int wm = (wave >> 2) * 64, wn = (wave & 3) * 64;
  const int K = D_;
  const int NT = 16;  // K/64

  const int srow = tid >> 3;   // 0..63
  const int sc8 = tid & 7;
  const short* gA = &A[(size_t)m0 * K];
  const short* gB = &Bt[(size_t)n0 * K];

  auto stageA = [&](int t, int p) {  // p = 0..1 (64 rows each)
    const int row = p * 64 + srow;
    load_lds16(&gA[(size_t)row * K + t * 64 + ((sc8 ^ (row & 7)) * 8)],
               &lds[t % 3][row * 64 + sc8 * 8]);
  };
  auto stageB = [&](int t, int p) {  // p = 0..3 (64 rows each)
    const int row = p * 64 + srow;
    load_lds16(&gB[(size_t)row * K + t * 64 + ((sc8 ^ (row & 7)) * 8)],
               &lds[t % 3][8192 + row * 64 + sc8 * 8]);
  };

  f32x4 acc[4][4];
#pragma unroll
  for (int i = 0; i < 4; i++)
#pragma unroll
    for (int j = 0; j < 4; j++) acc[i][j] = (f32x4){0.f, 0.f, 0.f, 0.f};

  // Prologue: tile0 (6 loads, oldest) then tile1 (6).
  stageA(0, 0); stageA(0, 1);
  for (int p = 0; p < 4; p++) stageB(0, p);
  stageA(1, 0); stageA(1, 1);
  for (int p = 0; p < 4; p++) stageB(1, p);
  asm volatile("s_waitcnt vmcnt(6)" ::: "memory");  // tile0's 6 landed
  __builtin_amdgcn_sched_barrier(0);
  __builtin_amdgcn_s_barrier();

  for (int t = 0; t < NT; t++) {
    const short* la = lds[t % 3];
    const short* lb = la + 8192;

    bf16x8 bfr[4][2];
    // ---- phase 0: i-strips 0,1 ----
    {
      bf16x8 af[2][2];
#pragma unroll
      for (int j = 0; j < 4; j++)
#pragma unroll
        for (int kk = 0; kk < 2; kk++)
          bfr[j][kk] = *(const bf16x8*)&lb[(wn + j * 16 + col) * 64 +
                                           (((kk * 4 + quad) ^ (col & 7)) * 8)];
#pragma unroll
      for (int f = 0; f < 2; f++)
#pragma unroll
        for (int kk = 0; kk < 2; kk++)
          af[f][kk] = *(const bf16x8*)&la[(wm + f * 16 + col) * 64 +
                                          (((kk * 4 + quad) ^ (col & 7)) * 8)];
      if (t + 2 < NT) { stageB(t + 2, 0); stageB(t + 2, 1); stageB(t + 2, 2); }
      __builtin_amdgcn_sched_barrier(0);
      __builtin_amdgcn_s_barrier();
      asm volatile("s_waitcnt lgkmcnt(0)" ::: "memory");
      __builtin_amdgcn_sched_barrier(0);
      __builtin_amdgcn_s_setprio(1);
#pragma unroll
      for (int f = 0; f < 2; f++)
#pragma unroll
        for (int j = 0; j < 4; j++)
#pragma unroll
          for (int kk = 0; kk < 2; kk++)
            acc[f][j] = __builtin_amdgcn_mfma_f32_16x16x32_bf16(
                af[f][kk], bfr[j][kk], acc[f][j], 0, 0, 0);
      __builtin_amdgcn_s_setprio(0);
      __builtin_amdgcn_sched_barrier(0);
      __builtin_amdgcn_s_barrier();
    }
    // ---- phase 1: i-strips 2,3 ----
    {
      bf16x8 af[2][2];
#pragma unroll
      for (int f = 0; f < 2; f++)
#pragma unroll
        for (int kk = 0; kk < 2; kk++)
          af[f][kk] = *(const bf16x8*)&la[(wm + (2 + f) * 16 + col) * 64 +
                                          (((kk * 4 + quad) ^ (col & 7)) * 8)];
      if (t + 2 < NT) { stageB(t + 2, 3); stageA(t + 2, 0); stageA(t + 2, 1); }
      __builtin_amdgcn_sched_barrier(0);
      __builtin_amdgcn_s_barrier();
      asm volatile("s_waitcnt lgkmcnt(0)" ::: "memory");
      __builtin_amdgcn_sched_barrier(0);
      __builtin_amdgcn_s_setprio(1);
#pragma unroll
      for (int f = 0; f < 2; f++)
#pragma unroll
        for (int j = 0; j < 4; j++)
#pragma unroll
          for (int kk = 0; kk < 2; kk++)
            acc[2 + f][j] = __builtin_amdgcn_mfma_f32_16x16x32_bf16(
                af[f][kk], bfr[j][kk], acc[2 + f][j], 0, 0, 0);
      __builtin_amdgcn_s_setprio(0);
      if (t + 2 < NT)      { asm volatile("s_waitcnt vmcnt(6)" ::: "memory"); }
      else if (t + 1 < NT) { asm volatile("s_waitcnt vmcnt(0)" ::: "memory"); }
      __builtin_amdgcn_sched_barrier(0);
      __builtin_amdgcn_s_barrier();
    }
  }

  if (nsel < 2) {
    short* C = nsel ? Ck : Cq;
    const float sc = nsel == 0 ? 0.18033688f : 1.0f;  // 0.125 * log2(e)
    for (int j = 0; j < 4; j++) {
      const int gn = n0 + wn + j * 16 + col;
      for (int i = 0; i < 4; i++) {
        const int gm = m0 + wm + i * 16 + quad * 4;
        for (int r = 0; r < 4; r++)
          C[(size_t)(gm + r) * D_ + gn] = f2bf(acc[i][j][r] * sc);
      }
    }
  } else {
    for (int j = 0; j < 4; j++) {
      const int gn = n0 + wn + j * 16 + col;
      for (int i = 0; i < 4; i++) {
        const int gm = m0 + wm + i * 16 + quad * 4;
        const int bb = gm >> 11, s = gm & 2047;
        short4 o;
        o.x = f2bf(acc[i][j][0]); o.y = f2bf(acc[i][j][1]);
        o.z = f2bf(acc[i][j][2]); o.w = f2bf(acc[i][j][3]);
        *(short4*)&Cvt[((size_t)bb * D_ + gn) * (size_t)S_ + s] = o;
      }
    }
  }
}

// Output projection on the same v3 schedule. grid (M/128, N/256) = (64, 4)
// = 256 blocks = EXACTLY 1 resident round at 1 block/CU -> zero tail.
// Mechanical port of gemm_qkv8 (r8/r9-verified): nsel removed, fp32+bias out.
__global__ __launch_bounds__(512, 2) void gemm_bb8(const short* __restrict__ A,
                                                   const short* __restrict__ Bt,
                                                   float* __restrict__ C,
                                                   const float* __restrict__ bias) {
  __shared__ __align__(16) short lds[3][24576];  // [buf][A 128x64 | B 256x64]
  const int tid = threadIdx.x;
  const int wave = tid >> 6, lane = tid & 63;
  const int quad = lane >> 4, col = lane & 15;
  const int n0 = blockIdx.y * 256;
  const int m0 = blockIdx.x * 128;
  const int wm = (wave >> 2) * 64, wn = (wave & 3) * 64;
  const int K = D_, N = D_;
  const int NT = 16;  // K/64

  const int srow = tid >> 3;
  const int sc8 = tid & 7;
  const short* gA = &A[(size_t)m0 * K];
  const short* gB = &Bt[(size_t)n0 * K];

  auto stageA = [&](int t, int p) {
    const int row = p * 64 + srow;
    load_lds16(&gA[(size_t)row * K + t * 64 + ((sc8 ^ (row & 7)) * 8)],
               &lds[t % 3][row * 64 + sc8 * 8]);
  };
  auto stageB = [&](int t, int p) {
    const int row = p * 64 + srow;
    load_lds16(&gB[(size_t)row * K + t * 64 + ((sc8 ^ (row & 7)) * 8)],
               &lds[t % 3][8192 + row * 64 + sc8 * 8]);
  };

  f32x4 acc[4][4];
#pragma unroll
  for (int i = 0; i < 4; i++)
#pragma unroll
    for (int j = 0; j < 4; j++) acc[i][j] = (f32x4){0.f, 0.f, 0.f, 0.f};

  stageA(0, 0); stageA(0, 1);
  for (int p = 0; p < 4; p++) stageB(0, p);
  stageA(1, 0); stageA(1, 1);
  for (int p = 0; p < 4; p++) stageB(1, p);
  asm volatile("s_waitcnt vmcnt(6)" ::: "memory");
  __builtin_amdgcn_sched_barrier(0);
  __builtin_amdgcn_s_barrier();

  for (int t = 0; t < NT; t++) {
    const short* la = lds[t % 3];
    const short* lb = la + 8192;

    bf16x8 bfr[4][2];
    {
      bf16x8 af[2][2];
#pragma unroll
      for (int j = 0; j < 4; j++)
#pragma unroll
        for (int kk = 0; kk < 2; kk++)
          bfr[j][kk] = *(const bf16x8*)&lb[(wn + j * 16 + col) * 64 +
                                           (((kk * 4 + quad) ^ (col & 7)) * 8)];
#pragma unroll
      for (int f = 0; f < 2; f++)
#pragma unroll
        for (int kk = 0; kk < 2; kk++)
          af[f][kk] = *(const bf16x8*)&la[(wm + f * 16 + col) * 64 +
                                          (((kk * 4 + quad) ^ (col & 7)) * 8)];
      if (t + 2 < NT) { stageB(t + 2, 0); stageB(t + 2, 1); stageB(t + 2, 2); }
      __builtin_amdgcn_sched_barrier(0);
      __builtin_amdgcn_s_barrier();
      asm volatile("s_waitcnt lgkmcnt(0)" ::: "memory");
      __builtin_amdgcn_sched_barrier(0);
      __builtin_amdgcn_s_setprio(1);
#pragma unroll
      for (int f = 0; f < 2; f++)
#pragma unroll
        for (int j = 0; j < 4; j++)
#pragma unroll
          for (int kk = 0; kk < 2; kk++)
            acc[f][j] = __builtin_amdgcn_mfma_f32_16x16x32_bf16(
                af[f][kk], bfr[j][kk], acc[f][j], 0, 0, 0);
      __builtin_amdgcn_s_setprio(0);
      __builtin_amdgcn_sched_barrier(0);
      __builtin_amdgcn_s_barrier();
    }
    {
      bf16x8 af[2][2];
#pragma unroll
      for (int f = 0; f < 2; f++)
#pragma unroll
        for (int kk = 0; kk < 2; kk++)
          af[f][kk] = *(const bf16x8*)&la[(wm + (2 + f) * 16 + col) * 64 +
                                          (((kk * 4 + quad) ^ (col & 7)) * 8)];
      if (t + 2 < NT) { stageB(t + 2, 3); stageA(t + 2, 0); stageA(t + 2, 1); }
      __builtin_amdgcn_sched_barrier(0);
      __builtin_amdgcn_s_barrier();
      asm volatile("s_waitcnt lgkmcnt(0)" ::: "memory");
      __builtin_amdgcn_sched_barrier(0);
      __builtin_amdgcn_s_setprio(1);
#pragma unroll
      for (int f = 0; f < 2; f++)
#pragma unroll
        for (int j = 0; j < 4; j++)
#pragma unroll
          for (int kk = 0; kk < 2; kk++)
            acc[2 + f][j] = __builtin_amdgcn_mfma_f32_16x16x32_bf16(
                af[f][kk], bfr[j][kk], acc[2 + f][j], 0, 0, 0);
      __builtin_amdgcn_s_setprio(0);
      if (t + 2 < NT)      { asm volatile("s_waitcnt vmcnt(6)" ::: "memory"); }
      else if (t + 1 < NT) { asm volatile("s_waitcnt vmcnt(0)" ::: "memory"); }
      __builtin_amdgcn_sched_barrier(0);
      __builtin_amdgcn_s_barrier();
    }
  }

  for (int j = 0; j < 4; j++) {
    const int gn = n0 + wn + j * 16 + col;
    const float bv = bias[gn];
    for (int i = 0; i < 4; i++) {
      const int gm = m0 + wm + i * 16 + quad * 4;
      for (int r = 0; r < 4; r++)
        C[(size_t)(gm + r) * N + gn] = acc[i][j][r] + bv;
    }
  }
}

// Flash attention v10: v9 + raw v_exp_f32 via __builtin_amdgcn_exp2f (libm
// exp2f carries ~5 VALU ops of range handling x16/tile -> r9 VALUBusy 58%).
// Inputs pre-scaled (|z| <~ 30), masked after -> numerically safe.
__global__ __launch_bounds__(256) void flash_attn6(const short* __restrict__ Q,
                                                   const short* __restrict__ Kt,
                                                   const short* __restrict__ Vt,
                                                   short* __restrict__ O) {
  __shared__ __align__(16) short lK[2][64 * 64];
  __shared__ __align__(16) short lV[2][64 * 64];
  __shared__ __align__(16) short pl[4][16 * 64];
  const int tid = threadIdx.x, wave = tid >> 6, lane = tid & 63;
  const int quad = lane >> 4, col = lane & 15;
  const int bh = blockIdx.x;
  const int b = bh >> 4, h = bh & 15;
  const size_t qkbase = (size_t)b * S_ * D_ + (size_t)h * HS_;
  const size_t vtbase = ((size_t)b * D_ + (size_t)h * HS_) * (size_t)S_;

  const int srow = tid >> 3;
  const int scg = (tid & 7) ^ (srow & 7);
  const int cs0 = (quad ^ (col & 7)) * 8;
  const int cs1 = ((quad + 4) ^ (col & 7)) * 8;
  short* plw = pl[wave];

  bf16x8 ones;
  for (int i = 0; i < 8; i++) ones[i] = (short)0x3F80;

  int nb = 0;

  for (int half = 0; half < 2; half++) {
    const int s = half ? (int)blockIdx.y : 31 - (int)blockIdx.y;
    const int qmin = s * 64 + wave * 16;
    const int L = s;

    load_lds16(&Kt[qkbase + (size_t)srow * D_ + scg * 8],        &lK[nb][tid * 8]);
    load_lds16(&Kt[qkbase + (size_t)(32 + srow) * D_ + scg * 8], &lK[nb][2048 + tid * 8]);
    load_lds16(&Vt[vtbase + (size_t)srow * S_ + scg * 8],        &lV[nb][tid * 8]);
    load_lds16(&Vt[vtbase + (size_t)(srow + 32) * S_ + scg * 8], &lV[nb][2048 + tid * 8]);
    const int cur0 = nb;
    nb ^= 1;

    bf16x8 qf[2];
    for (int x = 0; x < 2; x++)
      qf[x] = *(const bf16x8*)&Q[qkbase + (size_t)(qmin + col) * D_ + x * 32 + quad * 8];

    f32x4 oacc[4], lacc;
    for (int dt = 0; dt < 4; dt++) oacc[dt] = (f32x4){0.f, 0.f, 0.f, 0.f};
    lacc = (f32x4){0.f, 0.f, 0.f, 0.f};

    for (int nt = 0; nt <= L; nt++) {
      const int n0 = nt * 64;
      const int cur = cur0 ^ (nt & 1);
      __syncthreads();
      if (nt < L) {
        const int nn = n0 + 64;
        load_lds16(&Kt[qkbase + (size_t)(nn + srow) * D_ + scg * 8],      &lK[nb][tid * 8]);
        load_lds16(&Kt[qkbase + (size_t)(nn + 32 + srow) * D_ + scg * 8], &lK[nb][2048 + tid * 8]);
        load_lds16(&Vt[vtbase + (size_t)srow * S_ + nn + scg * 8],        &lV[nb][tid * 8]);
        load_lds16(&Vt[vtbase + (size_t)(srow + 32) * S_ + nn + scg * 8], &lV[nb][2048 + tid * 8]);
        nb ^= 1;
      }

      const short* lKc = lK[cur];
      const short* lVc = lV[cur];
      const bool needM = (nt == L);

      bf16x8 kf[4][2];
      for (int t = 0; t < 4; t++) {
        const int rb = (t * 16 + col) * 64;
        kf[t][0] = *(const bf16x8*)&lKc[rb + cs0];
        kf[t][1] = *(const bf16x8*)&lKc[rb + cs1];
      }

      const int qg = qmin + col;
      for (int t = 0; t < 4; t++) {
        f32x4 z = (f32x4){0.f, 0.f, 0.f, 0.f};
        __builtin_amdgcn_s_setprio(1);
        z = __builtin_amdgcn_mfma_f32_16x16x32_bf16(kf[t][0], qf[0], z, 0, 0, 0);
        z = __builtin_amdgcn_mfma_f32_16x16x32_bf16(kf[t][1], qf[1], z, 0, 0, 0);
        __builtin_amdgcn_s_setprio(0);
        float p0 = fexp2(z[0]);
        float p1 = fexp2(z[1]);
        float p2 = fexp2(z[2]);
        float p3 = fexp2(z[3]);
        if (needM) {
          const int kv = n0 + t * 16 + quad * 4;
          if (kv + 0 > qg) p0 = 0.f;
          if (kv + 1 > qg) p1 = 0.f;
          if (kv + 2 > qg) p2 = 0.f;
          if (kv + 3 > qg) p3 = 0.f;
        }
        unsigned d0 = __builtin_amdgcn_perm(fbits(p1), fbits(p0), 0x07060302u);
        unsigned d1 = __builtin_amdgcn_perm(fbits(p3), fbits(p2), 0x07060302u);
        const int cc = (2 * t + (quad >> 1)) ^ (col & 7);
        uint2 w; w.x = d0; w.y = d1;
        *(uint2*)&plw[col * 64 + cc * 8 + (quad & 1) * 4] = w;
      }

      for (int h2 = 0; h2 < 2; h2++) {
        const int cgo = ((h2 * 4 + quad) ^ (col & 7)) * 8;
        const bf16x8 pf = *(const bf16x8*)&plw[col * 64 + cgo];
        bf16x8 vf[4];
        for (int dt = 0; dt < 4; dt++)
          vf[dt] = *(const bf16x8*)&lVc[(dt * 16 + col) * 64 + cgo];
        __builtin_amdgcn_s_setprio(1);
        lacc = __builtin_amdgcn_mfma_f32_16x16x32_bf16(pf, ones, lacc, 0, 0, 0);
        for (int dt = 0; dt < 4; dt++)
          oacc[dt] = __builtin_amdgcn_mfma_f32_16x16x32_bf16(pf, vf[dt], oacc[dt], 0, 0, 0);
        __builtin_amdgcn_s_setprio(0);
      }
    }

    for (int r = 0; r < 4; r++) {
      const float inv = 1.f / lacc[r];
      const size_t row = qkbase + (size_t)(qmin + quad * 4 + r) * D_;
      for (int dt = 0; dt < 4; dt++)
        O[row + dt * 16 + col] = f2bf(oacc[dt][r] * inv);
    }
  }
}

// ---- legacy fallback kernels (small-ws paths) ----
__global__ __launch_bounds__(256) void gemm_ff(const float* __restrict__ A,
                                               const float* __restrict__ Bt,
                                               short* __restrict__ C,
                                               int M, int N, int K) {
  __shared__ __align__(16) short lA[128 * 32];
  __shared__ __align__(16) short lB[128 * 32];
  const int tid = threadIdx.x;
  const int wave = tid >> 6, lane = tid & 63;
  const int quad = lane >> 4, col = lane & 15;
  const int m0 = blockIdx.y * 128, n0 = blockIdx.x * 128;
  const int wm = (wave >> 1) * 64, wn = (wave & 1) * 64;
  const int srow2 = tid >> 1;
  const int sc = (tid & 1) * 16;

  f32x4 acc[4][4];
  for (int i = 0; i < 4; i++)
    for (int j = 0; j < 4; j++) acc[i][j] = (f32x4){0.f, 0.f, 0.f, 0.f};

  for (int k0 = 0; k0 < K; k0 += 32) {
    __syncthreads();
    {
      const float4* ga = (const float4*)&A[(size_t)(m0 + srow2) * K + k0 + sc];
      const float4 v0 = ga[0], v1 = ga[1], v2 = ga[2], v3 = ga[3];
      bf16x8 p0, p1;
      p0[0] = f2bf(v0.x); p0[1] = f2bf(v0.y); p0[2] = f2bf(v0.z); p0[3] = f2bf(v0.w);
      p0[4] = f2bf(v1.x); p0[5] = f2bf(v1.y); p0[6] = f2bf(v1.z); p0[7] = f2bf(v1.w);
      p1[0] = f2bf(v2.x); p1[1] = f2bf(v2.y); p1[2] = f2bf(v2.z); p1[3] = f2bf(v2.w);
      p1[4] = f2bf(v3.x); p1[5] = f2bf(v3.y); p1[6] = f2bf(v3.z); p1[7] = f2bf(v3.w);
      *(bf16x8*)&lA[srow2 * 32 + sc]     = p0;
      *(bf16x8*)&lA[srow2 * 32 + sc + 8] = p1;
    }
    {
      const float4* gb = (const float4*)&Bt[(size_t)(n0 + srow2) * K + k0 + sc];
      const float4 v0 = gb[0], v1 = gb[1], v2 = gb[2], v3 = gb[3];
      bf16x8 p0, p1;
      p0[0] = f2bf(v0.x); p0[1] = f2bf(v0.y); p0[2] = f2bf(v0.z); p0[3] = f2bf(v0.w);
      p0[4] = f2bf(v1.x); p0[5] = f2bf(v1.y); p0[6] = f2bf(v1.z); p0[7] = f2bf(v1.w);
      p1[0] = f2bf(v2.x); p1[1] = f2bf(v2.y); p1[2] = f2bf(v2.z); p1[3] = f2bf(v2.w);
      p1[4] = f2bf(v3.x); p1[5] = f2bf(v3.y); p1[6] = f2bf(v3.z); p1[7] = f2bf(v3.w);
      *(bf16x8*)&lB[srow2 * 32 + sc]     = p0;
      *(bf16x8*)&lB[srow2 * 32 + sc + 8] = p1;
    }
    __syncthreads();
    {
      bf16x8 af[4], bfr[4];
      for (int i = 0; i < 4; i++) af[i]  = *(const bf16x8*)&lA[(wm + i * 16 + col) * 32 + quad * 8];
      for (int j = 0; j < 4; j++) bfr[j] = *(const bf16x8*)&lB[(wn + j * 16 + col) * 32 + quad * 8];
      for (int i = 0; i < 4; i++)
        for (int j = 0; j < 4; j++)
          acc[i][j] = __builtin_amdgcn_mfma_f32_16x16x32_bf16(af[i], bfr[j], acc[i][j], 0, 0, 0);
    }
  }

  for (int j = 0; j < 4; j++) {
    const int gn = n0 + wn + j * 16 + col;
    for (int i = 0; i < 4; i++) {
      const int gm = m0 + wm + i * 16 + quad * 4;
      for (int r = 0; r < 4; r++)
        C[(size_t)(gm + r) * N + gn] = f2bf(acc[i][j][r]);
    }
  }
}

__global__ __launch_bounds__(256) void gemm_out_bf(const short* __restrict__ A,
                                                   const float* __restrict__ Bt,
                                                   float* __restrict__ C,
                                                   const float* __restrict__ bias,
                                                   int M, int N, int K) {
  __shared__ __align__(16) short lA[128 * 32];
  __shared__ __align__(16) short lB[128 * 32];
  const int tid = threadIdx.x;
  const int wave = tid >> 6, lane = tid & 63;
  const int quad = lane >> 4, col = lane & 15;
  const int m0 = blockIdx.y * 128, n0 = blockIdx.x * 128;
  const int wm = (wave >> 1) * 64, wn = (wave & 1) * 64;
  const int srow = wave * 32 + (lane >> 2);
  const int scol = (lane & 3) * 8;
  const int srow2 = tid >> 1;
  const int sc = (tid & 1) * 16;

  f32x4 acc[4][4];
  for (int i = 0; i < 4; i++)
    for (int j = 0; j < 4; j++) acc[i][j] = (f32x4){0.f, 0.f, 0.f, 0.f};

  for (int k0 = 0; k0 < K; k0 += 32) {
    __syncthreads();
    load_lds16(&A[(size_t)(m0 + srow) * K + k0 + scol],      &lA[srow * 32 + scol]);
    load_lds16(&A[(size_t)(m0 + srow + 16) * K + k0 + scol], &lA[(srow + 16) * 32 + scol]);
    {
      const float4* gb = (const float4*)&Bt[(size_t)(n0 + srow2) * K + k0 + sc];
      const float4 v0 = gb[0], v1 = gb[1], v2 = gb[2], v3 = gb[3];
      bf16x8 p0, p1;
      p0[0] = f2bf(v0.x); p0[1] = f2bf(v0.y); p0[2] = f2bf(v0.z); p0[3] = f2bf(v0.w);
      p0[4] = f2bf(v1.x); p0[5] = f2bf(v1.y); p0[6] = f2bf(v1.z); p0[7] = f2bf(v1.w);
      p1[0] = f2bf(v2.x); p1[1] = f2bf(v2.y); p1[2] = f2bf(v2.z); p1[3] = f2bf(v2.w);
      p1[4] = f2bf(v3.x); p1[5] = f2bf(v3.y); p1[6] = f2bf(v3.z); p1[7] = f2bf(v3.w);
      *(bf16x8*)&lB[srow2 * 32 + sc]     = p0;
      *(bf16x8*)&lB[srow2 * 32 + sc + 8] = p1;
    }
    __syncthreads();
    {
      bf16x8 af[4], bfr[4];
      for (int i = 0; i < 4; i++) af[i]  = *(const bf16x8*)&lA[(wm + i * 16 + col) * 32 + quad * 8];
      for (int j = 0; j < 4; j++) bfr[j] = *(const bf16x8*)&lB[(wn + j * 16 + col) * 32 + quad * 8];
      for (int i = 0; i < 4; i++)
        for (int j = 0; j < 4; j++)
          acc[i][j] = __builtin_amdgcn_mfma_f32_16x16x32_bf16(af[i], bfr[j], acc[i][j], 0, 0, 0);
    }
  }

  for (int j = 0; j < 4; j++) {
    const int gn = n0 + wn + j * 16 + col;
    const float bv = bias ? bias[gn] : 0.f;
    for (int i = 0; i < 4; i++) {
      const int gm = m0 + wm + i * 16 + quad * 4;
      for (int r = 0; r < 4; r++)
        C[(size_t)(gm + r) * N + gn] = acc[i][j][r] + bv;
    }
  }
}

__global__ __launch_bounds__(64) void flash_attn(const short* __restrict__ Q,
                                                 const short* __restrict__ K,
                                                 const short* __restrict__ V,
                                                 short* __restrict__ O) {
  __shared__ __align__(16) short pl[16 * 40];
  const int lane = threadIdx.x;
  const int quad = lane >> 4, col = lane & 15;
  const int blk = blockIdx.x;
  const int qt = blk & 127;
  const int bh = blk >> 7;
  const int b = bh >> 4, h = bh & 15;
  const int q0 = qt * 16;
  const size_t base = (size_t)b * S_ * D_ + (size_t)h * HS_;

  const bf16x8 qf0 = *(const bf16x8*)&Q[base + (size_t)(q0 + col) * D_ + quad * 8];
  const bf16x8 qf1 = *(const bf16x8*)&Q[base + (size_t)(q0 + col) * D_ + 32 + quad * 8];

  float mr[4], lr[4];
  f32x4 oacc[4];
  for (int r = 0; r < 4; r++) { mr[r] = -1e30f; lr[r] = 0.f; }
  for (int dt = 0; dt < 4; dt++) oacc[dt] = (f32x4){0.f, 0.f, 0.f, 0.f};

  const int ntiles = (q0 + 15) / 32 + 1;
  for (int nt = 0; nt < ntiles; nt++) {
    const int n0 = nt * 32;
    f32x4 s[2];
    s[0] = (f32x4){0.f, 0.f, 0.f, 0.f};
    s[1] = (f32x4){0.f, 0.f, 0.f, 0.f};
    for (int t = 0; t < 2; t++) {
      const short* kp = &K[base + (size_t)(n0 + t * 16 + col) * D_ + quad * 8];
      const bf16x8 kf0 = *(const bf16x8*)kp;
      const bf16x8 kf1 = *(const bf16x8*)(kp + 32);
      s[t] = __builtin_amdgcn_mfma_f32_16x16x32_bf16(qf0, kf0, s[t], 0, 0, 0);
      s[t] = __builtin_amdgcn_mfma_f32_16x16x32_bf16(qf1, kf1, s[t], 0, 0, 0);
    }
    for (int r = 0; r < 4; r++) {
      const int mg = q0 + quad * 4 + r;
      float s0 = s[0][r] * 0.125f; if (n0 + col > mg)      s0 = -1e30f;
      float s1 = s[1][r] * 0.125f; if (n0 + 16 + col > mg) s1 = -1e30f;
      float tm = fmaxf(s0, s1);
      for (int off = 1; off < 16; off <<= 1) tm = fmaxf(tm, __shfl_xor(tm, off));
      const float mnew = fmaxf(mr[r], tm);
      const float alpha = __expf(mr[r] - mnew);
      mr[r] = mnew;
      const float p0 = __expf(s0 - mnew);
      const float p1 = __expf(s1 - mnew);
      float ps = p0 + p1;
      for (int off = 1; off < 16; off <<= 1) ps += __shfl_xor(ps, off);
      lr[r] = lr[r] * alpha + ps;
      for (int dt = 0; dt < 4; dt++) oacc[dt][r] *= alpha;
      pl[(quad * 4 + r) * 40 + col]      = f2bf(p0);
      pl[(quad * 4 + r) * 40 + 16 + col] = f2bf(p1);
    }
    const bf16x8 pf = *(const bf16x8*)&pl[col * 40 + quad * 8];
    for (int dt = 0; dt < 4; dt++) {
      bf16x8 vf;
      const short* vp = &V[base + (size_t)(n0 + quad * 8) * D_ + dt * 16 + col];
      for (int j = 0; j < 8; j++) vf[j] = vp[(size_t)j * D_];
      oacc[dt] = __builtin_amdgcn_mfma_f32_16x16x32_bf16(pf, vf, oacc[dt], 0, 0, 0);
    }
  }

  for (int r = 0; r < 4; r++) {
    const float inv = 1.f / lr[r];
    const size_t row = base + (size_t)(q0 + quad * 4 + r) * D_;
    for (int dt = 0; dt < 4; dt++)
      O[row + dt * 16 + col] = f2bf(oacc[dt][r] * inv);
  }
}

extern "C" void kernel_launch(void* const* d_in, const int* in_sizes, int n_in,
                              void* d_out, int out_size, void* d_ws, size_t ws_size,
                              hipStream_t stream) {
  const float* x  = (const float*)d_in[0];
  const float* Wk = (const float*)d_in[1];
  const float* Wq = (const float*)d_in[2];
  const float* Wv = (const float*)d_in[3];
  const float* Wo = (const float*)d_in[4];
  const float* bo = (const float*)d_in[5];
  float* out = (float*)d_out;

  char* ws = (char*)d_ws;
  const size_t MiB = 1u << 20;
  const int M = B_ * S_, N = D_, K = D_;
  const int nx = M * D_, nw = D_ * D_;

  if (ws_size >= 88 * MiB) {
    short* xb    = (short*)(ws);
    short* wkb   = (short*)(ws + 16 * MiB);
    short* wqb   = (short*)(ws + 18 * MiB);
    short* wvb   = (short*)(ws + 20 * MiB);
    short* wob   = (short*)(ws + 22 * MiB);
    short* q_ws  = (short*)(ws + 24 * MiB);
    short* k_ws  = (short*)(ws + 40 * MiB);
    short* vt_ws = (short*)(ws + 56 * MiB);
    short* a_ws  = (short*)(ws + 72 * MiB);

    hipLaunchKernelGGL(cvt_f32_bf16, dim3(nx / 1024), dim3(256), 0, stream, x, xb, nx);
    hipLaunchKernelGGL(cvt4_f32_bf16, dim3(nw / 1024, 4), dim3(256), 0, stream,
                       Wq, Wk, Wv, Wo, wqb, wkb, wvb, wob, nw);
    hipLaunchKernelGGL(gemm_qkv8, dim3(M / 128, 12), dim3(512), 0, stream,
                       xb, wqb, wkb, wvb, q_ws, k_ws, vt_ws);
    hipLaunchKernelGGL(flash_attn6, dim3(B_ * H_, 16), dim3(256), 0, stream,
                       q_ws, k_ws, vt_ws, a_ws);
    hipLaunchKernelGGL(gemm_bb8, dim3(M / 128, N / 256), dim3(512), 0, stream,
                       a_ws, wob, out, bo);
  } else if (ws_size >= 64 * MiB) {
    short* q_ws = (short*)(ws);
    short* k_ws = (short*)(ws + 16 * MiB);
    short* v_ws = (short*)(ws + 32 * MiB);
    short* a_ws = (short*)(ws + 48 * MiB);
    dim3 gg(N / 128, M / 128), gb(256);
    hipLaunchKernelGGL(gemm_ff, gg, gb, 0, stream, x, Wq, q_ws, M, N, K);
    hipLaunchKernelGGL(gemm_ff, gg, gb, 0, stream, x, Wk, k_ws, M, N, K);
    hipLaunchKernelGGL(gemm_ff, gg, gb, 0, stream, x, Wv, v_ws, M, N, K);
    hipLaunchKernelGGL(flash_attn, dim3(B_ * H_ * (S_ / 16)), dim3(64), 0, stream, q_ws, k_ws, v_ws, a_ws);
    hipLaunchKernelGGL(gemm_out_bf, gg, gb, 0, stream, a_ws, Wo, out, bo, M, N, K);
  } else {
    short* q_ws = (short*)(ws);
    short* k_ws = (short*)(ws + 4 * MiB);
    short* v_ws = (short*)(ws + 8 * MiB);
    short* a_ws = (short*)(ws + 12 * MiB);
    const int Mb = S_;
    dim3 gg(N / 128, Mb / 128), gb(256);
    for (int b = 0; b < B_; b++) {
      const float* xb = x + (size_t)b * S_ * D_;
      float* ob = out + (size_t)b * S_ * D_;
      hipLaunchKernelGGL(gemm_ff, gg, gb, 0, stream, xb, Wq, q_ws, Mb, N, K);
      hipLaunchKernelGGL(gemm_ff, gg, gb, 0, stream, xb, Wk, k_ws, Mb, N, K);
      hipLaunchKernelGGL(gemm_ff, gg, gb, 0, stream, xb, Wv, v_ws, Mb, N, K);
      hipLaunchKernelGGL(flash_attn, dim3(H_ * (S_ / 16)), dim3(64), 0, stream, q_ws, k_ws, v_ws, a_ws);
      hipLaunchKernelGGL(gemm_out_bf, gg, gb, 0, stream, a_ws, Wo, ob, bo, Mb, N, K);
    }
  }
}